// Round 24
// baseline (762.294 us; speedup 1.0000x reference)
//
#include <hip/hip_runtime.h>
#include <math.h>

#define NB 4
#define NV 8
#define NC 32
#define NG 65536
#define IMGW 256
#define NBI 32               // NB*NV
#define RSPLIT 8             // pixel-range split for k2/k3 (8192 bins)
#define RBINS (NG / RSPLIT)
#define K4SPLIT 32           // k4 sub-range split (2048 bins per block)
#define K4BINS (NG / K4SPLIT)
#define K4CAP 18176          // LDS slot capacity (mean 16384 + 14 sigma); 79KB -> 2 blocks/CU
#define START_STRIDE 65544   // 65536 + sentinel + pad
#define SORT_STRIDE (1u << 20) // padded slot capacity per bi
#define SENTINEL (8u << 27)  // widx=8 (w=0); byte-row masks to 0

static constexpr long long STACKED_ELEMS = (long long)NB * NV * NG * NC; // 67108864

typedef __attribute__((ext_vector_type(8))) short short8;
typedef __attribute__((ext_vector_type(4))) float f32x4;
typedef __attribute__((ext_vector_type(4))) unsigned int u32x4;
typedef __attribute__((ext_vector_type(4))) float f32x4c;

// ---------------- ws layout ----------------
static constexpr size_t OFF_AT    = 0;      // 1 KB
static constexpr size_t OFF_RTOT  = 1024;   // 256 u32
static constexpr size_t OFF_RBASE = 2048;   // 32*9 u32
static constexpr size_t OFF_START = 4096;
static constexpr size_t OFF_CNT   = OFF_START + (size_t)NBI * START_STRIDE * 4;
static constexpr size_t OFF_PIX   = OFF_CNT + (size_t)NBI * NG * 4;
static constexpr size_t OFF_SORT  = OFF_PIX + (size_t)NBI * NV * NG * 2;
static constexpr size_t OFF_FB16  = OFF_SORT + (size_t)NBI * SORT_STRIDE * 4; // 33.6 MB slab

__device__ __forceinline__ unsigned short f2bf(float f)
{
    unsigned int u = __float_as_uint(f);
    return (unsigned short)((u + 0x7FFFu + ((u >> 16) & 1u)) >> 16);
}

// ---------------- adjacency ----------------
__global__ __launch_bounds__(256) void adj_kernel(const float* __restrict__ ext,
                                                  float* __restrict__ A_out,
                                                  float* __restrict__ At_out)
{
    __shared__ float ctr[NB * NV][3];
    __shared__ float Dsh[NB * NV * NV];
    int t = threadIdx.x;
    if (t < NB * NV) {
        const float* E = ext + t * 16;
        #pragma unroll
        for (int i = 0; i < 3; i++) {
            float s = E[0 * 4 + i] * E[0 * 4 + 3]
                    + E[1 * 4 + i] * E[1 * 4 + 3]
                    + E[2 * 4 + i] * E[2 * 4 + 3];
            ctr[t][i] = -s;
        }
    }
    __syncthreads();
    {
        int b = t >> 6, i = (t >> 3) & 7, j = t & 7;
        float dx = ctr[b * 8 + i][0] - ctr[b * 8 + j][0];
        float dy = ctr[b * 8 + i][1] - ctr[b * 8 + j][1];
        float dz = ctr[b * 8 + i][2] - ctr[b * 8 + j][2];
        Dsh[t] = dx * dx + dy * dy + dz * dz;
    }
    __syncthreads();
    if (t < NB * NV) {
        int ri = t & 7;
        const float* drow = &Dsh[t * 8];
        bool chosen[8] = {false, false, false, false, false, false, false, false};
        for (int n = 0; n < 3; n++) {
            int best = -1; float bs = -3.0e38f;
            for (int j2 = 0; j2 < 8; j2++) {
                if (j2 == ri || chosen[j2]) continue;
                float s = -drow[j2];
                if (s > bs) { bs = s; best = j2; }
            }
            chosen[best] = true;
        }
        float row[8]; float deg = 0.f;
        #pragma unroll
        for (int j2 = 0; j2 < 8; j2++) {
            float a = 0.f;
            if (j2 == ri)        a = 1.0f;
            else if (chosen[j2]) a = 1.0f / (1.0f + sqrtf(drow[j2] + 1e-6f));
            row[j2] = a; deg += a;
        }
        float dn = deg + (deg == 0.f ? 1.f : 0.f);
        #pragma unroll
        for (int j2 = 0; j2 < 8; j2++) {
            A_out[t * 8 + j2]  = row[j2];
            At_out[t * 8 + j2] = row[j2] / dn;
        }
    }
}

// ---------------- k1: pixel precompute ----------------
__global__ __launch_bounds__(256) void k1_pix(const float2* __restrict__ xy,
                                              unsigned short* __restrict__ pixarr)
{
    unsigned int base = blockIdx.x * 1024 + threadIdx.x;
    #pragma unroll
    for (int k = 0; k < 4; k++) {
        unsigned int tid = base + k * 256; // [b][j][i][g]
        float2 p = xy[tid];
        float px = fminf(fmaxf(rintf(p.x), 0.f), (float)(IMGW - 1));
        float py = fminf(fmaxf(rintf(p.y), 0.f), (float)(IMGW - 1));
        unsigned int pix = (unsigned int)py * IMGW + (unsigned int)px;
        unsigned int g = tid & 0xFFFFu;
        unsigned int i = (tid >> 16) & 7u;
        unsigned int j = (tid >> 19) & 7u;
        unsigned int b = tid >> 22;
        unsigned int bi = (b << 3) | i;
        pixarr[(((bi << 3) | j) << 16) | g] = (unsigned short)pix; // [bi][j][g]
    }
}

// ---------------- k2: LDS histogram + padded range totals; XCD-swizzled ----------------
__global__ __launch_bounds__(1024) void k2_hist(const unsigned short* __restrict__ pixarr,
                                                unsigned int* __restrict__ cnt,
                                                unsigned int* __restrict__ rtot)
{
    __shared__ unsigned int hist[RBINS]; // 32 KB
    int t = threadIdx.x;
    unsigned int bi = blockIdx.x & 31u;  // XCD = bi%8
    unsigned int r  = blockIdx.x >> 5;
    unsigned int r0 = r * RBINS;
    for (int k = t; k < RBINS; k += 1024) hist[k] = 0;
    __syncthreads();
    const uint4* src = (const uint4*)(pixarr + ((size_t)bi << 19));
    for (int it = 0; it < 16; it++) {
        uint4 vv[4];
        #pragma unroll
        for (int q = 0; q < 4; q++)
            vv[q] = src[t + (it * 4 + q) * 1024];
        #pragma unroll
        for (int q = 0; q < 4; q++) {
            const unsigned int* vw = (const unsigned int*)&vv[q];
            #pragma unroll
            for (int h = 0; h < 4; h++) {
                unsigned int w = vw[h];
                unsigned int p0 = (w & 0xFFFFu) - r0;
                unsigned int p1 = (w >> 16) - r0;
                if (p0 < RBINS) atomicAdd(&hist[p0], 1u);
                if (p1 < RBINS) atomicAdd(&hist[p1], 1u);
            }
        }
    }
    __syncthreads();
    unsigned int* dst = cnt + ((size_t)bi << 16) + r0;
    unsigned int psum = 0;
    for (int k = t; k < RBINS; k += 1024) {
        unsigned int v = hist[k];
        dst[k] = v;
        psum += (v + 7u) & ~7u;
    }
    __syncthreads();
    hist[t] = psum;
    __syncthreads();
    for (int off = 512; off; off >>= 1) {
        if (t < off) hist[t] += hist[t + off];
        __syncthreads();
    }
    if (t == 0) rtot[bi * 8 + r] = hist[0];
}

// ---------------- k3b: per-bi scan of 8 padded range totals ----------------
__global__ __launch_bounds__(64) void k3b_rscan(const unsigned int* __restrict__ rtot,
                                                unsigned int* __restrict__ rbase)
{
    int t = threadIdx.x;
    if (t < 32) {
        unsigned int run = 0;
        #pragma unroll
        for (int q = 0; q < 8; q++) {
            rbase[t * 9 + q] = run;
            run += rtot[t * 8 + q];
        }
        rbase[t * 9 + 8] = run;
    }
}

// ---------------- k3c: coalesced per-(bi,r) bin scan via LDS ----------------
__global__ __launch_bounds__(1024) void k3c_scan(const unsigned int* __restrict__ cnt,
                                                 const unsigned int* __restrict__ rbase,
                                                 unsigned int* __restrict__ start)
{
    __shared__ unsigned int lc[RBINS]; // 32 KB
    __shared__ unsigned int bs[1024];
    int t = threadIdx.x;
    unsigned int bi = blockIdx.x & 31u;
    unsigned int r  = blockIdx.x >> 5;
    unsigned int r0 = r * RBINS;
    const unsigned int* c = cnt + ((size_t)bi << 16) + r0;
    #pragma unroll
    for (int q = 0; q < 8; q++)
        lc[q * 1024 + t] = (c[q * 1024 + t] + 7u) & ~7u; // coalesced, padded
    __syncthreads();
    unsigned int v[8]; unsigned int s = 0;
    #pragma unroll
    for (int k = 0; k < 8; k++) { v[k] = s; s += lc[t * 8 + k]; } // contiguous run
    bs[t] = s;
    __syncthreads();
    for (int off = 1; off < 1024; off <<= 1) {
        unsigned int u = (t >= off) ? bs[t - off] : 0u;
        __syncthreads();
        bs[t] += u;
        __syncthreads();
    }
    unsigned int base = rbase[bi * 9 + r] + bs[t] - s; // exclusive prefix
    #pragma unroll
    for (int k = 0; k < 8; k++) lc[t * 8 + k] = base + v[k];
    __syncthreads();
    unsigned int* st_ = start + (size_t)bi * START_STRIDE + r0;
    #pragma unroll
    for (int q = 0; q < 8; q++)
        st_[q * 1024 + t] = lc[q * 1024 + t]; // coalesced
    if (r == 7 && t == 0)
        start[(size_t)bi * START_STRIDE + NG] = rbase[bi * 9 + 8];
}

// ---------------- k4: LDS-staged counting sort (coalesced flush); 2 blocks/CU ----------------
__global__ __launch_bounds__(1024, 8) void k4_fill(const unsigned short* __restrict__ pixarr,
                                                   const unsigned int* __restrict__ start,
                                                   unsigned int* __restrict__ sorted)
{
    extern __shared__ unsigned int dyn[];
    unsigned int* cur = dyn;          // 2048 relative cursors
    unsigned int* buf = dyn + K4BINS; // K4CAP payload slots
    int t = threadIdx.x;
    unsigned int bi  = blockIdx.x & 31u;  // XCD = bi%8
    unsigned int sub = blockIdx.x >> 5;
    unsigned int bin0 = sub * K4BINS;
    const unsigned int* stg = start + (size_t)bi * START_STRIDE;
    unsigned int base = stg[bin0];
    unsigned int end  = stg[bin0 + K4BINS];
    unsigned int size = end - base;
    const uint4* src = (const uint4*)(pixarr + ((size_t)bi << 19));
    unsigned int* dstbase = sorted + (size_t)bi * SORT_STRIDE;

    if (size <= K4CAP) {
        // fast path: stage in LDS
        #pragma unroll 2
        for (int k = t; k < K4BINS; k += 1024) cur[k] = stg[bin0 + k] - base;
        for (int k = t; k < (int)size; k += 1024) buf[k] = SENTINEL;
        __syncthreads();
        for (int it = 0; it < 16; it++) {
            uint4 vv[4];
            #pragma unroll
            for (int q = 0; q < 4; q++)
                vv[q] = src[t + (it * 4 + q) * 1024];
            #pragma unroll
            for (int q = 0; q < 4; q++) {
                unsigned int m0 = (t + (it * 4 + q) * 1024) * 8;
                const unsigned int* vw = (const unsigned int*)&vv[q];
                #pragma unroll
                for (int h = 0; h < 8; h++) {
                    unsigned int w = vw[h >> 1];
                    unsigned int pv = ((h & 1) ? (w >> 16) : (w & 0xFFFFu)) - bin0;
                    if (pv < K4BINS) {
                        unsigned int slot = atomicAdd(&cur[pv], 1u); // LDS atomic
                        unsigned int m = m0 + h;                     // (j<<16)|g
                        buf[slot] = ((m >> 16) << 27) | (m << 6);    // (j<<27)|(rowidx<<6)
                    }
                }
            }
        }
        __syncthreads();
        // coalesced flush (size is a multiple of 8)
        uint4* gdst = (uint4*)(dstbase + base);
        const uint4* lsrc = (const uint4*)buf;
        int n4 = (int)(size >> 2);
        for (int k = t; k < n4; k += 1024) gdst[k] = lsrc[k];
    } else {
        // slow path: absolute cursors, direct scatter + sentinel fill
        #pragma unroll 2
        for (int k = t; k < K4BINS; k += 1024) cur[k] = stg[bin0 + k];
        __syncthreads();
        for (int it = 0; it < 16; it++) {
            uint4 vv[4];
            #pragma unroll
            for (int q = 0; q < 4; q++)
                vv[q] = src[t + (it * 4 + q) * 1024];
            #pragma unroll
            for (int q = 0; q < 4; q++) {
                unsigned int m0 = (t + (it * 4 + q) * 1024) * 8;
                const unsigned int* vw = (const unsigned int*)&vv[q];
                #pragma unroll
                for (int h = 0; h < 8; h++) {
                    unsigned int w = vw[h >> 1];
                    unsigned int pv = ((h & 1) ? (w >> 16) : (w & 0xFFFFu)) - bin0;
                    if (pv < K4BINS) {
                        unsigned int slot = atomicAdd(&cur[pv], 1u);
                        unsigned int m = m0 + h;
                        dstbase[slot] = ((m >> 16) << 27) | (m << 6);
                    }
                }
            }
        }
        __syncthreads();
        for (int k = t; k < K4BINS; k += 1024) {
            unsigned int e = stg[bin0 + k + 1];
            for (unsigned int x = cur[k]; x < e; x++) dstbase[x] = SENTINEL;
        }
    }
}

// ---------------- kf_conv: feat[b] f32 -> bf16 slab (NT read, coalesced) ----------------
__global__ __launch_bounds__(256) void kf_conv(const float* __restrict__ src,
                                               ushort4* __restrict__ dst)
{
    unsigned int base = blockIdx.x * 1024 + threadIdx.x; // 4096 blocks x 4 float4
    #pragma unroll
    for (int k = 0; k < 4; k++) {
        unsigned int idx = base + k * 256;
        f32x4c v = __builtin_nontemporal_load((const f32x4c*)(src) + idx);
        ushort4 o;
        o.x = f2bf(v.x); o.y = f2bf(v.y); o.z = f2bf(v.z); o.w = f2bf(v.w);
        dst[idx] = o;
    }
}

// ---------------- b_gather: bf16 rows (64B), uint2/lane, MFMA epilogue; per-b ----------------
__global__ __launch_bounds__(256, 4) void b_gather(
    const unsigned short* __restrict__ fb16,   // this b's slab [j][g][c] bf16
    const unsigned short* __restrict__ pixarr,
    const unsigned int* __restrict__ start,
    const unsigned int* __restrict__ sorted,
    const float* __restrict__ Wlin,
    const float* __restrict__ blin,
    const float* __restrict__ At,
    float* __restrict__ out,
    int b)
{
    __shared__ float At9[NBI][16];     // 9-wide weight rows (index 8 = 0.0)
    int t = threadIdx.x;
    int c4 = t & 7;                    // channel quad index
    int grp = t >> 3;                  // 0..31 = row within block

    unsigned int bidx = blockIdx.x;
    unsigned int i  = bidx & 7u;           // XCD-pinned view
    unsigned int gc = bidx >> 3;           // 0..2047
    unsigned int bi = ((unsigned int)b << 3) | i;
    unsigned int g0 = gc << 5;             // 32 rows per block
    unsigned int g = g0 + grp;
    unsigned int pix = pixarr[(((bi << 3) | i) << 16) | g];

    At9[t >> 3][t & 7] = At[t];
    At9[t >> 3][8 + (t & 7)] = 0.f;

    // preload W fragments (L2-hot, uniform)
    int l = t & 63;
    short8 bf0, bf1;
    #pragma unroll
    for (int j = 0; j < 8; j++) {
        int kk = (l >> 4) * 8 + j;
        bf0[j] = (short)f2bf(Wlin[kk * NC + (l & 15)]);
        bf1[j] = (short)f2bf(Wlin[kk * NC + 16 + (l & 15)]);
    }

    const unsigned int* st = start + (size_t)bi * START_STRIDE;
    unsigned int s0 = st[pix];
    unsigned int e0 = st[pix + 1];
    const unsigned int* pl = sorted + (size_t)bi * SORT_STRIDE;
    const char* fbB = (const char*)fb16;
    unsigned int cb = c4 << 3;         // uint2 byte offset within 64B bf16 row
    __syncthreads();

    const float* Atrow = At9[bi];
    float ax = 0.f, ay = 0.f, az = 0.f, aw = 0.f, wsum = 0.f;
    for (unsigned int k0 = s0; k0 < e0; k0 += 8) {
        u32x4 pa = __builtin_nontemporal_load((const u32x4*)(pl + k0));
        u32x4 pb = __builtin_nontemporal_load((const u32x4*)(pl + k0 + 4));
        unsigned int pv[8] = {pa.x, pa.y, pa.z, pa.w, pb.x, pb.y, pb.z, pb.w};
        uint2 uv[8];
        #pragma unroll
        for (int h = 0; h < 8; h++)
            uv[h] = *(const uint2*)(fbB + ((pv[h] & 0x01FFFFC0u) | cb)); // sentinel -> row 0
        float wv[8];
        #pragma unroll
        for (int h = 0; h < 8; h++)
            wv[h] = Atrow[pv[h] >> 27];                                  // sentinel -> 0.0
        #pragma unroll
        for (int h = 0; h < 8; h++) {
            ax = fmaf(wv[h], __uint_as_float(uv[h].x << 16), ax);
            ay = fmaf(wv[h], __uint_as_float(uv[h].x & 0xFFFF0000u), ay);
            az = fmaf(wv[h], __uint_as_float(uv[h].y << 16), az);
            aw = fmaf(wv[h], __uint_as_float(uv[h].y & 0xFFFF0000u), aw);
            wsum += wv[h];
        }
    }

    // ---- wave-local MFMA epilogue (no LDS, no barrier); 8 rows per wave ----
    int r = l & 15;
    int kb = l >> 4;
    int s0l = (((r & 7) << 3) | (kb << 1)) & 63;  // j=0..3 source lane
    int s1l = s0l | 1;                            // j=4..7 source lane
    float v0x = __shfl(ax, s0l, 64), v0y = __shfl(ay, s0l, 64);
    float v0z = __shfl(az, s0l, 64), v0w = __shfl(aw, s0l, 64);
    float v1x = __shfl(ax, s1l, 64), v1y = __shfl(ay, s1l, 64);
    float v1z = __shfl(az, s1l, 64), v1w = __shfl(aw, s1l, 64);
    short8 af;
    if (r < 8) {
        af[0] = (short)f2bf(v0x); af[1] = (short)f2bf(v0y);
        af[2] = (short)f2bf(v0z); af[3] = (short)f2bf(v0w);
        af[4] = (short)f2bf(v1x); af[5] = (short)f2bf(v1y);
        af[6] = (short)f2bf(v1z); af[7] = (short)f2bf(v1w);
    } else {
        af = short8{0, 0, 0, 0, 0, 0, 0, 0};
    }
    float bias0 = blin[l & 15];
    float bias1 = blin[16 + (l & 15)];
    f32x4 c0, c1;
    #pragma unroll
    for (int q = 0; q < 4; q++) {
        int row = kb * 4 + q;                       // C/D row for reg q
        float wvx = __shfl(wsum, (row << 3) & 63, 64);
        wvx = (row < 8) ? wvx : 0.f;
        c0[q] = bias0 * wvx;
        c1[q] = bias1 * wvx;
    }
    c0 = __builtin_amdgcn_mfma_f32_16x16x32_bf16(af, bf0, c0, 0, 0, 0);
    c1 = __builtin_amdgcn_mfma_f32_16x16x32_bf16(af, bf1, c1, 0, 0, 0);
    if (l < 32) {
        size_t rowbase = (((size_t)bi << 16) | g0) + (t >> 6) * 8; // wave's 8 rows
        #pragma unroll
        for (int q = 0; q < 4; q++) {
            size_t rr = rowbase + (l >> 4) * 4 + q;  // rows 0-7 across lanes 0-31
            __builtin_nontemporal_store(c0[q], &out[rr * NC + (l & 15)]);
            __builtin_nontemporal_store(c1[q], &out[rr * NC + 16 + (l & 15)]);
        }
    }
}

extern "C" void kernel_launch(void* const* d_in, const int* in_sizes, int n_in,
                              void* d_out, int out_size, void* d_ws, size_t ws_size,
                              hipStream_t stream)
{
    const float* features = (const float*)d_in[0];
    const float* xy       = (const float*)d_in[1];
    const float* ext      = (const float*)d_in[2];
    const float* Wlin     = (const float*)d_in[3];
    const float* blin     = (const float*)d_in[4];
    float* out = (float*)d_out;

    char* ws = (char*)d_ws;
    float*          At     = (float*)(ws + OFF_AT);
    unsigned int*   rtot   = (unsigned int*)(ws + OFF_RTOT);
    unsigned int*   rbase  = (unsigned int*)(ws + OFF_RBASE);
    unsigned int*   start  = (unsigned int*)(ws + OFF_START);
    unsigned int*   cnt    = (unsigned int*)(ws + OFF_CNT);
    unsigned short* pixarr = (unsigned short*)(ws + OFF_PIX);
    unsigned int*   sorted = (unsigned int*)(ws + OFF_SORT);
    unsigned short* fb16   = (unsigned short*)(ws + OFF_FB16);

    // allow 79 KB dynamic LDS for k4_fill (idempotent, graph-safe)
    static const size_t k4_lds = (K4BINS + K4CAP) * sizeof(unsigned int);
    hipFuncSetAttribute((const void*)k4_fill,
                        hipFuncAttributeMaxDynamicSharedMemorySize, (int)k4_lds);

    adj_kernel<<<1, 256, 0, stream>>>(ext, out + STACKED_ELEMS, At);

    k1_pix<<<(NB * NV * NV * NG) / 1024, 256, 0, stream>>>((const float2*)xy, pixarr);
    k2_hist<<<NBI * RSPLIT, 1024, 0, stream>>>(pixarr, cnt, rtot);
    k3b_rscan<<<1, 64, 0, stream>>>(rtot, rbase);
    k3c_scan<<<NBI * RSPLIT, 1024, 0, stream>>>(cnt, rbase, start);
    k4_fill<<<NBI * K4SPLIT, 1024, k4_lds, stream>>>(pixarr, start, sorted);

    for (int b = 0; b < NB; b++) {
        const float* src = features + (((size_t)b) << 19) * NC;
        kf_conv<<<4096, 256, 0, stream>>>(src, (ushort4*)fb16);
        b_gather<<<16384, 256, 0, stream>>>(fb16, pixarr, start, sorted,
                                            Wlin, blin, At, out, b);
    }
}

// Round 25
// 599.128 us; speedup vs baseline: 1.2723x; 1.2723x over previous
//
#include <hip/hip_runtime.h>
#include <math.h>

#define NB 4
#define NV 8
#define NC 32
#define NG 65536
#define IMGW 256
#define NBI 32               // NB*NV
#define RSPLIT 8             // k2/k3 range split (8192 bins)
#define RBINS (NG / RSPLIT)
#define K4SPLIT 32           // sub-range split (2048 bins)
#define K4BINS (NG / K4SPLIT)
#define K4CAP 24576          // k4b LDS slot capacity (mean padded ~23.7K)
#define CAP4A 1272           // k4a per-bucket LDS capacity (mean 1024 + 8 sigma)
#define PART_STRIDE 19456    // parts segment stride (mean 16384 + 24 sigma)
#define START_STRIDE 65544
#define SORT_STRIDE (1u << 20)
#define SENTINEL (8u << 27)  // widx=8 (w=0); byte-row masks to 0

static constexpr long long STACKED_ELEMS = (long long)NB * NV * NG * NC; // 67108864

typedef __attribute__((ext_vector_type(8))) short short8;
typedef __attribute__((ext_vector_type(4))) float f32x4;
typedef __attribute__((ext_vector_type(4))) unsigned int u32x4;
typedef __attribute__((ext_vector_type(4))) float f32x4c;

// ---------------- ws layout ----------------
static constexpr size_t OFF_AT    = 0;          // 1 KB
static constexpr size_t OFF_RTOT  = 1024;       // 256 u32
static constexpr size_t OFF_RBASE = 2048;       // 32*9 u32
static constexpr size_t OFF_GSC   = 3584;       // 1024 u32 global sub-cursors
static constexpr size_t OFF_START = 8192;
static constexpr size_t OFF_CNT   = OFF_START + (size_t)NBI * START_STRIDE * 4;
static constexpr size_t OFF_PIX   = OFF_CNT + (size_t)NBI * NG * 4;
static constexpr size_t OFF_SORT  = OFF_PIX + (size_t)NBI * NV * NG * 2;
static constexpr size_t OFF_FB16  = OFF_SORT + (size_t)NBI * SORT_STRIDE * 4;
static constexpr size_t OFF_PARTS = OFF_FB16;   // overlay: parts live only in sort phase
// peak: max(OFF_PARTS + 1024*PART_STRIDE*4 = 264.3 MB, OFF_FB16 + 33.6 MB = 218.1 MB) < 268.4 MB proven

__device__ __forceinline__ unsigned short f2bf(float f)
{
    unsigned int u = __float_as_uint(f);
    return (unsigned short)((u + 0x7FFFu + ((u >> 16) & 1u)) >> 16);
}

// ---------------- adjacency ----------------
__global__ __launch_bounds__(256) void adj_kernel(const float* __restrict__ ext,
                                                  float* __restrict__ A_out,
                                                  float* __restrict__ At_out)
{
    __shared__ float ctr[NB * NV][3];
    __shared__ float Dsh[NB * NV * NV];
    int t = threadIdx.x;
    if (t < NB * NV) {
        const float* E = ext + t * 16;
        #pragma unroll
        for (int i = 0; i < 3; i++) {
            float s = E[0 * 4 + i] * E[0 * 4 + 3]
                    + E[1 * 4 + i] * E[1 * 4 + 3]
                    + E[2 * 4 + i] * E[2 * 4 + 3];
            ctr[t][i] = -s;
        }
    }
    __syncthreads();
    {
        int b = t >> 6, i = (t >> 3) & 7, j = t & 7;
        float dx = ctr[b * 8 + i][0] - ctr[b * 8 + j][0];
        float dy = ctr[b * 8 + i][1] - ctr[b * 8 + j][1];
        float dz = ctr[b * 8 + i][2] - ctr[b * 8 + j][2];
        Dsh[t] = dx * dx + dy * dy + dz * dz;
    }
    __syncthreads();
    if (t < NB * NV) {
        int ri = t & 7;
        const float* drow = &Dsh[t * 8];
        bool chosen[8] = {false, false, false, false, false, false, false, false};
        for (int n = 0; n < 3; n++) {
            int best = -1; float bs = -3.0e38f;
            for (int j2 = 0; j2 < 8; j2++) {
                if (j2 == ri || chosen[j2]) continue;
                float s = -drow[j2];
                if (s > bs) { bs = s; best = j2; }
            }
            chosen[best] = true;
        }
        float row[8]; float deg = 0.f;
        #pragma unroll
        for (int j2 = 0; j2 < 8; j2++) {
            float a = 0.f;
            if (j2 == ri)        a = 1.0f;
            else if (chosen[j2]) a = 1.0f / (1.0f + sqrtf(drow[j2] + 1e-6f));
            row[j2] = a; deg += a;
        }
        float dn = deg + (deg == 0.f ? 1.f : 0.f);
        #pragma unroll
        for (int j2 = 0; j2 < 8; j2++) {
            A_out[t * 8 + j2]  = row[j2];
            At_out[t * 8 + j2] = row[j2] / dn;
        }
    }
}

// ---------------- k1: pixel precompute ----------------
__global__ __launch_bounds__(256) void k1_pix(const float2* __restrict__ xy,
                                              unsigned short* __restrict__ pixarr)
{
    unsigned int base = blockIdx.x * 1024 + threadIdx.x;
    #pragma unroll
    for (int k = 0; k < 4; k++) {
        unsigned int tid = base + k * 256; // [b][j][i][g]
        float2 p = xy[tid];
        float px = fminf(fmaxf(rintf(p.x), 0.f), (float)(IMGW - 1));
        float py = fminf(fmaxf(rintf(p.y), 0.f), (float)(IMGW - 1));
        unsigned int pix = (unsigned int)py * IMGW + (unsigned int)px;
        unsigned int g = tid & 0xFFFFu;
        unsigned int i = (tid >> 16) & 7u;
        unsigned int j = (tid >> 19) & 7u;
        unsigned int b = tid >> 22;
        unsigned int bi = (b << 3) | i;
        pixarr[(((bi << 3) | j) << 16) | g] = (unsigned short)pix; // [bi][j][g]
    }
}

// ---------------- k2: LDS histogram + padded range totals; XCD-swizzled ----------------
__global__ __launch_bounds__(1024) void k2_hist(const unsigned short* __restrict__ pixarr,
                                                unsigned int* __restrict__ cnt,
                                                unsigned int* __restrict__ rtot)
{
    __shared__ unsigned int hist[RBINS]; // 32 KB
    int t = threadIdx.x;
    unsigned int bi = blockIdx.x & 31u;  // XCD = bi%8
    unsigned int r  = blockIdx.x >> 5;
    unsigned int r0 = r * RBINS;
    for (int k = t; k < RBINS; k += 1024) hist[k] = 0;
    __syncthreads();
    const uint4* src = (const uint4*)(pixarr + ((size_t)bi << 19));
    for (int it = 0; it < 16; it++) {
        uint4 vv[4];
        #pragma unroll
        for (int q = 0; q < 4; q++)
            vv[q] = src[t + (it * 4 + q) * 1024];
        #pragma unroll
        for (int q = 0; q < 4; q++) {
            const unsigned int* vw = (const unsigned int*)&vv[q];
            #pragma unroll
            for (int h = 0; h < 4; h++) {
                unsigned int w = vw[h];
                unsigned int p0 = (w & 0xFFFFu) - r0;
                unsigned int p1 = (w >> 16) - r0;
                if (p0 < RBINS) atomicAdd(&hist[p0], 1u);
                if (p1 < RBINS) atomicAdd(&hist[p1], 1u);
            }
        }
    }
    __syncthreads();
    unsigned int* dst = cnt + ((size_t)bi << 16) + r0;
    unsigned int psum = 0;
    for (int k = t; k < RBINS; k += 1024) {
        unsigned int v = hist[k];
        dst[k] = v;
        psum += (v + 7u) & ~7u;
    }
    __syncthreads();
    hist[t] = psum;
    __syncthreads();
    for (int off = 512; off; off >>= 1) {
        if (t < off) hist[t] += hist[t + off];
        __syncthreads();
    }
    if (t == 0) rtot[bi * 8 + r] = hist[0];
}

// ---------------- k3b: per-bi scan of 8 padded range totals ----------------
__global__ __launch_bounds__(64) void k3b_rscan(const unsigned int* __restrict__ rtot,
                                                unsigned int* __restrict__ rbase)
{
    int t = threadIdx.x;
    if (t < 32) {
        unsigned int run = 0;
        #pragma unroll
        for (int q = 0; q < 8; q++) {
            rbase[t * 9 + q] = run;
            run += rtot[t * 8 + q];
        }
        rbase[t * 9 + 8] = run;
    }
}

// ---------------- k3c: coalesced per-(bi,r) bin scan via LDS ----------------
__global__ __launch_bounds__(1024) void k3c_scan(const unsigned int* __restrict__ cnt,
                                                 const unsigned int* __restrict__ rbase,
                                                 unsigned int* __restrict__ start)
{
    __shared__ unsigned int lc[RBINS]; // 32 KB
    __shared__ unsigned int bs[1024];
    int t = threadIdx.x;
    unsigned int bi = blockIdx.x & 31u;
    unsigned int r  = blockIdx.x >> 5;
    unsigned int r0 = r * RBINS;
    const unsigned int* c = cnt + ((size_t)bi << 16) + r0;
    #pragma unroll
    for (int q = 0; q < 8; q++)
        lc[q * 1024 + t] = (c[q * 1024 + t] + 7u) & ~7u;
    __syncthreads();
    unsigned int v[8]; unsigned int s = 0;
    #pragma unroll
    for (int k = 0; k < 8; k++) { v[k] = s; s += lc[t * 8 + k]; }
    bs[t] = s;
    __syncthreads();
    for (int off = 1; off < 1024; off <<= 1) {
        unsigned int u = (t >= off) ? bs[t - off] : 0u;
        __syncthreads();
        bs[t] += u;
        __syncthreads();
    }
    unsigned int base = rbase[bi * 9 + r] + bs[t] - s;
    #pragma unroll
    for (int k = 0; k < 8; k++) lc[t * 8 + k] = base + v[k];
    __syncthreads();
    unsigned int* st_ = start + (size_t)bi * START_STRIDE + r0;
    #pragma unroll
    for (int q = 0; q < 8; q++)
        st_[q * 1024 + t] = lc[q * 1024 + t];
    if (r == 7 && t == 0)
        start[(size_t)bi * START_STRIDE + NG] = rbase[bi * 9 + 8];
}

// ---------------- k4a: radix partition into 32 sub-range segments (reads pixarr ONCE) ----------------
// 512 blocks: bi = blk&31, chunk = blk>>5 (32768 items each). LDS buckets + coarse
// global-cursor flush. Payload pv = (pix&0x7FF)<<19 | (j<<16) | g.
__global__ __launch_bounds__(1024) void k4a_part(const unsigned short* __restrict__ pixarr,
                                                 unsigned int* __restrict__ gsc,
                                                 unsigned int* __restrict__ parts)
{
    extern __shared__ unsigned int dynA[];
    unsigned int* cur32 = dynA;            // 32 cursors
    unsigned int* res   = dynA + 32;       // 32 flush bases
    unsigned int* lcnt  = dynA + 64;       // 32 flush counts
    unsigned int* lbuck = dynA + 96;       // 32 * CAP4A
    int t = threadIdx.x;
    unsigned int bi    = blockIdx.x & 31u; // XCD = bi%8
    unsigned int chunk = blockIdx.x >> 5;
    if (t < 32) cur32[t] = 0;
    __syncthreads();
    const uint4* src = (const uint4*)(pixarr + ((size_t)bi << 19)) + (chunk << 12);
    unsigned int idx0 = chunk << 15;
    #pragma unroll
    for (int it = 0; it < 4; it++) {
        uint4 v = src[t + it * 1024];
        unsigned int base_idx = idx0 + (t + it * 1024) * 8;
        const unsigned int* vw = (const unsigned int*)&v;
        #pragma unroll
        for (int h = 0; h < 8; h++) {
            unsigned int pix = (h & 1) ? (vw[h >> 1] >> 16) : (vw[h >> 1] & 0xFFFFu);
            unsigned int sub = pix >> 11;
            unsigned int pv = ((pix & 0x7FFu) << 19) | (base_idx + h);
            unsigned int slot = atomicAdd(&cur32[sub], 1u);
            if (slot < CAP4A) {
                lbuck[sub * CAP4A + slot] = pv;
            } else { // rare spill
                unsigned int gs = atomicAdd(&gsc[(bi << 5) | sub], 1u);
                parts[(size_t)((bi << 5) | sub) * PART_STRIDE + gs] = pv;
            }
        }
    }
    __syncthreads();
    if (t < 32) {
        unsigned int n = cur32[t];
        n = n < CAP4A ? n : CAP4A;
        lcnt[t] = n;
        res[t] = atomicAdd(&gsc[(bi << 5) | t], n);
    }
    __syncthreads();
    for (int s = 0; s < 32; s++) {
        unsigned int n = lcnt[s];
        unsigned int b0 = res[s];
        unsigned int* dst = parts + (size_t)((bi << 5) | s) * PART_STRIDE + b0;
        const unsigned int* sb = lbuck + s * CAP4A;
        for (unsigned int k = t; k < n; k += 1024) dst[k] = sb[k];
    }
}

// ---------------- k4b: LDS-staged counting sort from segment (coalesced flush) ----------------
__global__ __launch_bounds__(1024) void k4b_fill(const unsigned int* __restrict__ gsc,
                                                 const unsigned int* __restrict__ parts,
                                                 const unsigned int* __restrict__ start,
                                                 unsigned int* __restrict__ sorted)
{
    extern __shared__ unsigned int dynB[];
    unsigned int* cur = dynB;          // 2048 relative cursors
    unsigned int* buf = dynB + K4BINS; // K4CAP payload slots
    int t = threadIdx.x;
    unsigned int bi  = blockIdx.x & 31u; // XCD = bi%8
    unsigned int sub = blockIdx.x >> 5;
    unsigned int bin0 = sub * K4BINS;
    const unsigned int* stg = start + (size_t)bi * START_STRIDE;
    unsigned int base = stg[bin0];
    unsigned int end  = stg[bin0 + K4BINS];
    unsigned int size = end - base;
    unsigned int n = gsc[(bi << 5) | sub];
    const unsigned int* seg = parts + (size_t)((bi << 5) | sub) * PART_STRIDE;
    unsigned int* dstbase = sorted + (size_t)bi * SORT_STRIDE;

    if (size <= K4CAP) {
        // fast path: stage in LDS
        #pragma unroll 2
        for (int k = t; k < K4BINS; k += 1024) cur[k] = stg[bin0 + k] - base;
        for (int k = t; k < (int)size; k += 1024) buf[k] = SENTINEL;
        __syncthreads();
        for (unsigned int k = t; k < n; k += 1024) {
            unsigned int pv = seg[k];
            unsigned int bin = pv >> 19;
            unsigned int slot = atomicAdd(&cur[bin], 1u);
            buf[slot] = (((pv >> 16) & 7u) << 27) | ((pv & 0x7FFFFu) << 6);
        }
        __syncthreads();
        uint4* gdst = (uint4*)(dstbase + base);
        const uint4* lsrc = (const uint4*)buf;
        int n4 = (int)(size >> 2);
        for (int k = t; k < n4; k += 1024) gdst[k] = lsrc[k];
    } else {
        // slow path: absolute cursors, direct scatter + sentinel fill
        #pragma unroll 2
        for (int k = t; k < K4BINS; k += 1024) cur[k] = stg[bin0 + k];
        __syncthreads();
        for (unsigned int k = t; k < n; k += 1024) {
            unsigned int pv = seg[k];
            unsigned int bin = pv >> 19;
            unsigned int slot = atomicAdd(&cur[bin], 1u);
            dstbase[slot] = (((pv >> 16) & 7u) << 27) | ((pv & 0x7FFFFu) << 6);
        }
        __syncthreads();
        for (int k = t; k < K4BINS; k += 1024) {
            unsigned int e = stg[bin0 + k + 1];
            for (unsigned int x = cur[k]; x < e; x++) dstbase[x] = SENTINEL;
        }
    }
}

// ---------------- kf_conv: feat[b] f32 -> bf16 slab (NT read, coalesced) ----------------
__global__ __launch_bounds__(256) void kf_conv(const float* __restrict__ src,
                                               ushort4* __restrict__ dst)
{
    unsigned int base = blockIdx.x * 1024 + threadIdx.x;
    #pragma unroll
    for (int k = 0; k < 4; k++) {
        unsigned int idx = base + k * 256;
        f32x4c v = __builtin_nontemporal_load((const f32x4c*)(src) + idx);
        ushort4 o;
        o.x = f2bf(v.x); o.y = f2bf(v.y); o.z = f2bf(v.z); o.w = f2bf(v.w);
        dst[idx] = o;
    }
}

// ---------------- b_gather: bf16 rows (64B), uint2/lane, MFMA epilogue; per-b ----------------
__global__ __launch_bounds__(256, 4) void b_gather(
    const unsigned short* __restrict__ fb16,
    const unsigned short* __restrict__ pixarr,
    const unsigned int* __restrict__ start,
    const unsigned int* __restrict__ sorted,
    const float* __restrict__ Wlin,
    const float* __restrict__ blin,
    const float* __restrict__ At,
    float* __restrict__ out,
    int b)
{
    __shared__ float At9[NBI][16];
    int t = threadIdx.x;
    int c4 = t & 7;
    int grp = t >> 3;

    unsigned int bidx = blockIdx.x;
    unsigned int i  = bidx & 7u;
    unsigned int gc = bidx >> 3;
    unsigned int bi = ((unsigned int)b << 3) | i;
    unsigned int g0 = gc << 5;
    unsigned int g = g0 + grp;
    unsigned int pix = pixarr[(((bi << 3) | i) << 16) | g];

    At9[t >> 3][t & 7] = At[t];
    At9[t >> 3][8 + (t & 7)] = 0.f;

    int l = t & 63;
    short8 bf0, bf1;
    #pragma unroll
    for (int j = 0; j < 8; j++) {
        int kk = (l >> 4) * 8 + j;
        bf0[j] = (short)f2bf(Wlin[kk * NC + (l & 15)]);
        bf1[j] = (short)f2bf(Wlin[kk * NC + 16 + (l & 15)]);
    }

    const unsigned int* st = start + (size_t)bi * START_STRIDE;
    unsigned int s0 = st[pix];
    unsigned int e0 = st[pix + 1];
    const unsigned int* pl = sorted + (size_t)bi * SORT_STRIDE;
    const char* fbB = (const char*)fb16;
    unsigned int cb = c4 << 3;
    __syncthreads();

    const float* Atrow = At9[bi];
    float ax = 0.f, ay = 0.f, az = 0.f, aw = 0.f, wsum = 0.f;
    for (unsigned int k0 = s0; k0 < e0; k0 += 8) {
        u32x4 pa = __builtin_nontemporal_load((const u32x4*)(pl + k0));
        u32x4 pb = __builtin_nontemporal_load((const u32x4*)(pl + k0 + 4));
        unsigned int pv[8] = {pa.x, pa.y, pa.z, pa.w, pb.x, pb.y, pb.z, pb.w};
        uint2 uv[8];
        #pragma unroll
        for (int h = 0; h < 8; h++)
            uv[h] = *(const uint2*)(fbB + ((pv[h] & 0x01FFFFC0u) | cb));
        float wv[8];
        #pragma unroll
        for (int h = 0; h < 8; h++)
            wv[h] = Atrow[pv[h] >> 27];
        #pragma unroll
        for (int h = 0; h < 8; h++) {
            ax = fmaf(wv[h], __uint_as_float(uv[h].x << 16), ax);
            ay = fmaf(wv[h], __uint_as_float(uv[h].x & 0xFFFF0000u), ay);
            az = fmaf(wv[h], __uint_as_float(uv[h].y << 16), az);
            aw = fmaf(wv[h], __uint_as_float(uv[h].y & 0xFFFF0000u), aw);
            wsum += wv[h];
        }
    }

    int r = l & 15;
    int kb = l >> 4;
    int s0l = (((r & 7) << 3) | (kb << 1)) & 63;
    int s1l = s0l | 1;
    float v0x = __shfl(ax, s0l, 64), v0y = __shfl(ay, s0l, 64);
    float v0z = __shfl(az, s0l, 64), v0w = __shfl(aw, s0l, 64);
    float v1x = __shfl(ax, s1l, 64), v1y = __shfl(ay, s1l, 64);
    float v1z = __shfl(az, s1l, 64), v1w = __shfl(aw, s1l, 64);
    short8 af;
    if (r < 8) {
        af[0] = (short)f2bf(v0x); af[1] = (short)f2bf(v0y);
        af[2] = (short)f2bf(v0z); af[3] = (short)f2bf(v0w);
        af[4] = (short)f2bf(v1x); af[5] = (short)f2bf(v1y);
        af[6] = (short)f2bf(v1z); af[7] = (short)f2bf(v1w);
    } else {
        af = short8{0, 0, 0, 0, 0, 0, 0, 0};
    }
    float bias0 = blin[l & 15];
    float bias1 = blin[16 + (l & 15)];
    f32x4 c0, c1;
    #pragma unroll
    for (int q = 0; q < 4; q++) {
        int row = kb * 4 + q;
        float wvx = __shfl(wsum, (row << 3) & 63, 64);
        wvx = (row < 8) ? wvx : 0.f;
        c0[q] = bias0 * wvx;
        c1[q] = bias1 * wvx;
    }
    c0 = __builtin_amdgcn_mfma_f32_16x16x32_bf16(af, bf0, c0, 0, 0, 0);
    c1 = __builtin_amdgcn_mfma_f32_16x16x32_bf16(af, bf1, c1, 0, 0, 0);
    if (l < 32) {
        size_t rowbase = (((size_t)bi << 16) | g0) + (t >> 6) * 8;
        #pragma unroll
        for (int q = 0; q < 4; q++) {
            size_t rr = rowbase + (l >> 4) * 4 + q;
            __builtin_nontemporal_store(c0[q], &out[rr * NC + (l & 15)]);
            __builtin_nontemporal_store(c1[q], &out[rr * NC + 16 + (l & 15)]);
        }
    }
}

extern "C" void kernel_launch(void* const* d_in, const int* in_sizes, int n_in,
                              void* d_out, int out_size, void* d_ws, size_t ws_size,
                              hipStream_t stream)
{
    const float* features = (const float*)d_in[0];
    const float* xy       = (const float*)d_in[1];
    const float* ext      = (const float*)d_in[2];
    const float* Wlin     = (const float*)d_in[3];
    const float* blin     = (const float*)d_in[4];
    float* out = (float*)d_out;

    char* ws = (char*)d_ws;
    float*          At     = (float*)(ws + OFF_AT);
    unsigned int*   rtot   = (unsigned int*)(ws + OFF_RTOT);
    unsigned int*   rbase  = (unsigned int*)(ws + OFF_RBASE);
    unsigned int*   gsc    = (unsigned int*)(ws + OFF_GSC);
    unsigned int*   start  = (unsigned int*)(ws + OFF_START);
    unsigned int*   cnt    = (unsigned int*)(ws + OFF_CNT);
    unsigned short* pixarr = (unsigned short*)(ws + OFF_PIX);
    unsigned int*   sorted = (unsigned int*)(ws + OFF_SORT);
    unsigned int*   parts  = (unsigned int*)(ws + OFF_PARTS);
    unsigned short* fb16   = (unsigned short*)(ws + OFF_FB16);

    static const size_t k4a_lds = (96 + 32 * CAP4A) * sizeof(unsigned int);   // ~159.4 KB
    static const size_t k4b_lds = (K4BINS + K4CAP) * sizeof(unsigned int);    // 106.5 KB
    hipFuncSetAttribute((const void*)k4a_part,
                        hipFuncAttributeMaxDynamicSharedMemorySize, (int)k4a_lds);
    hipFuncSetAttribute((const void*)k4b_fill,
                        hipFuncAttributeMaxDynamicSharedMemorySize, (int)k4b_lds);

    adj_kernel<<<1, 256, 0, stream>>>(ext, out + STACKED_ELEMS, At);

    k1_pix<<<(NB * NV * NV * NG) / 1024, 256, 0, stream>>>((const float2*)xy, pixarr);
    k2_hist<<<NBI * RSPLIT, 1024, 0, stream>>>(pixarr, cnt, rtot);
    k3b_rscan<<<1, 64, 0, stream>>>(rtot, rbase);
    k3c_scan<<<NBI * RSPLIT, 1024, 0, stream>>>(cnt, rbase, start);

    hipMemsetAsync(gsc, 0, 1024 * sizeof(unsigned int), stream);
    k4a_part<<<NBI * 16, 1024, k4a_lds, stream>>>(pixarr, gsc, parts);
    k4b_fill<<<NBI * K4SPLIT, 1024, k4b_lds, stream>>>(gsc, parts, start, sorted);

    for (int b = 0; b < NB; b++) {
        const float* src = features + (((size_t)b) << 19) * NC;
        kf_conv<<<4096, 256, 0, stream>>>(src, (ushort4*)fb16);
        b_gather<<<16384, 256, 0, stream>>>(fb16, pixarr, start, sorted,
                                            Wlin, blin, At, out, b);
    }
}

// Round 26
// 592.108 us; speedup vs baseline: 1.2874x; 1.0119x over previous
//
#include <hip/hip_runtime.h>
#include <math.h>

#define NB 4
#define NV 8
#define NC 32
#define NG 65536
#define IMGW 256
#define NBI 32               // NB*NV
#define RSPLIT 8             // k2/k3 range split (8192 bins)
#define RBINS (NG / RSPLIT)
#define K4SPLIT 32           // sub-range split (2048 bins)
#define K4BINS (NG / K4SPLIT)
#define K4CAP 24576          // k4b LDS slot capacity (mean padded ~23.7K)
#define CAP4A 1272           // k4a per-bucket LDS capacity
#define PART_STRIDE 19456    // parts segment stride
#define START_STRIDE 65544
#define SORT_STRIDE (1u << 20)
#define SENTINEL (8u << 27)  // widx=8 (w=0); byte-row masks to 0

static constexpr long long STACKED_ELEMS = (long long)NB * NV * NG * NC; // 67108864

typedef __attribute__((ext_vector_type(8))) short short8;
typedef __attribute__((ext_vector_type(4))) float f32x4;
typedef __attribute__((ext_vector_type(4))) unsigned int u32x4;
typedef __attribute__((ext_vector_type(4))) float f32x4c;

// ---------------- ws layout ----------------
static constexpr size_t OFF_AT    = 0;          // 1 KB
static constexpr size_t OFF_RTOT  = 1024;       // 256 u32
static constexpr size_t OFF_GSC   = 3584;       // 1024 u32 global sub-cursors
static constexpr size_t OFF_START = 8192;
static constexpr size_t OFF_CNT   = OFF_START + (size_t)NBI * START_STRIDE * 4;
static constexpr size_t OFF_PIX   = OFF_CNT + (size_t)NBI * NG * 4;
static constexpr size_t OFF_SORT  = OFF_PIX + (size_t)NBI * NV * NG * 2;
static constexpr size_t OFF_FB16  = OFF_SORT + (size_t)NBI * SORT_STRIDE * 4;
static constexpr size_t OFF_PARTS = OFF_FB16;   // overlay: parts live only in sort phase

__device__ __forceinline__ unsigned short f2bf(float f)
{
    unsigned int u = __float_as_uint(f);
    return (unsigned short)((u + 0x7FFFu + ((u >> 16) & 1u)) >> 16);
}

// ---------------- k1: pixel precompute; last block computes adjacency ----------------
__global__ __launch_bounds__(256) void k1_pix(const float2* __restrict__ xy,
                                              unsigned short* __restrict__ pixarr,
                                              const float* __restrict__ ext,
                                              float* __restrict__ A_out,
                                              float* __restrict__ At_out)
{
    if (blockIdx.x == 16384) {
        // ---- adjacency path ----
        __shared__ float ctr[NB * NV][3];
        __shared__ float Dsh[NB * NV * NV];
        int t = threadIdx.x;
        if (t < NB * NV) {
            const float* E = ext + t * 16;
            #pragma unroll
            for (int i = 0; i < 3; i++) {
                float s = E[0 * 4 + i] * E[0 * 4 + 3]
                        + E[1 * 4 + i] * E[1 * 4 + 3]
                        + E[2 * 4 + i] * E[2 * 4 + 3];
                ctr[t][i] = -s;
            }
        }
        __syncthreads();
        {
            int b = t >> 6, i = (t >> 3) & 7, j = t & 7;
            float dx = ctr[b * 8 + i][0] - ctr[b * 8 + j][0];
            float dy = ctr[b * 8 + i][1] - ctr[b * 8 + j][1];
            float dz = ctr[b * 8 + i][2] - ctr[b * 8 + j][2];
            Dsh[t] = dx * dx + dy * dy + dz * dz;
        }
        __syncthreads();
        if (t < NB * NV) {
            int ri = t & 7;
            const float* drow = &Dsh[t * 8];
            bool chosen[8] = {false, false, false, false, false, false, false, false};
            for (int n = 0; n < 3; n++) {
                int best = -1; float bs = -3.0e38f;
                for (int j2 = 0; j2 < 8; j2++) {
                    if (j2 == ri || chosen[j2]) continue;
                    float s = -drow[j2];
                    if (s > bs) { bs = s; best = j2; }
                }
                chosen[best] = true;
            }
            float row[8]; float deg = 0.f;
            #pragma unroll
            for (int j2 = 0; j2 < 8; j2++) {
                float a = 0.f;
                if (j2 == ri)        a = 1.0f;
                else if (chosen[j2]) a = 1.0f / (1.0f + sqrtf(drow[j2] + 1e-6f));
                row[j2] = a; deg += a;
            }
            float dn = deg + (deg == 0.f ? 1.f : 0.f);
            #pragma unroll
            for (int j2 = 0; j2 < 8; j2++) {
                A_out[t * 8 + j2]  = row[j2];
                At_out[t * 8 + j2] = row[j2] / dn;
            }
        }
        return;
    }
    unsigned int base = blockIdx.x * 1024 + threadIdx.x;
    #pragma unroll
    for (int k = 0; k < 4; k++) {
        unsigned int tid = base + k * 256; // [b][j][i][g]
        float2 p = xy[tid];
        float px = fminf(fmaxf(rintf(p.x), 0.f), (float)(IMGW - 1));
        float py = fminf(fmaxf(rintf(p.y), 0.f), (float)(IMGW - 1));
        unsigned int pix = (unsigned int)py * IMGW + (unsigned int)px;
        unsigned int g = tid & 0xFFFFu;
        unsigned int i = (tid >> 16) & 7u;
        unsigned int j = (tid >> 19) & 7u;
        unsigned int b = tid >> 22;
        unsigned int bi = (b << 3) | i;
        pixarr[(((bi << 3) | j) << 16) | g] = (unsigned short)pix; // [bi][j][g]
    }
}

// ---------------- k2: LDS histogram + padded range totals; 8-deep loads ----------------
__global__ __launch_bounds__(1024) void k2_hist(const unsigned short* __restrict__ pixarr,
                                                unsigned int* __restrict__ cnt,
                                                unsigned int* __restrict__ rtot)
{
    __shared__ unsigned int hist[RBINS]; // 32 KB
    int t = threadIdx.x;
    unsigned int bi = blockIdx.x & 31u;  // XCD = bi%8
    unsigned int r  = blockIdx.x >> 5;
    unsigned int r0 = r * RBINS;
    for (int k = t; k < RBINS; k += 1024) hist[k] = 0;
    __syncthreads();
    const uint4* src = (const uint4*)(pixarr + ((size_t)bi << 19));
    for (int it = 0; it < 8; it++) {
        uint4 vv[8];
        #pragma unroll
        for (int q = 0; q < 8; q++)
            vv[q] = src[t + (it * 8 + q) * 1024]; // 8 loads in flight
        #pragma unroll
        for (int q = 0; q < 8; q++) {
            const unsigned int* vw = (const unsigned int*)&vv[q];
            #pragma unroll
            for (int h = 0; h < 4; h++) {
                unsigned int w = vw[h];
                unsigned int p0 = (w & 0xFFFFu) - r0;
                unsigned int p1 = (w >> 16) - r0;
                if (p0 < RBINS) atomicAdd(&hist[p0], 1u);
                if (p1 < RBINS) atomicAdd(&hist[p1], 1u);
            }
        }
    }
    __syncthreads();
    unsigned int* dst = cnt + ((size_t)bi << 16) + r0;
    unsigned int psum = 0;
    for (int k = t; k < RBINS; k += 1024) {
        unsigned int v = hist[k];
        dst[k] = v;
        psum += (v + 7u) & ~7u;
    }
    __syncthreads();
    hist[t] = psum;
    __syncthreads();
    for (int off = 512; off; off >>= 1) {
        if (t < off) hist[t] += hist[t + off];
        __syncthreads();
    }
    if (t == 0) rtot[bi * 8 + r] = hist[0];
}

// ---------------- k3c: coalesced per-(bi,r) bin scan; rbase computed in-block ----------------
__global__ __launch_bounds__(1024) void k3c_scan(const unsigned int* __restrict__ cnt,
                                                 const unsigned int* __restrict__ rtot,
                                                 unsigned int* __restrict__ start)
{
    __shared__ unsigned int lc[RBINS]; // 32 KB
    __shared__ unsigned int bs[1024];
    int t = threadIdx.x;
    unsigned int bi = blockIdx.x & 31u;
    unsigned int r  = blockIdx.x >> 5;
    unsigned int r0 = r * RBINS;
    // rbase: prefix over this bi's 8 range totals (redundant per block, trivial)
    unsigned int rb = 0, rtotal = 0;
    #pragma unroll
    for (int q = 0; q < 8; q++) {
        unsigned int v = rtot[bi * 8 + q];
        if ((unsigned int)q < r) rb += v;
        rtotal += v;
    }
    const unsigned int* c = cnt + ((size_t)bi << 16) + r0;
    #pragma unroll
    for (int q = 0; q < 8; q++)
        lc[q * 1024 + t] = (c[q * 1024 + t] + 7u) & ~7u;
    __syncthreads();
    unsigned int v[8]; unsigned int s = 0;
    #pragma unroll
    for (int k = 0; k < 8; k++) { v[k] = s; s += lc[t * 8 + k]; }
    bs[t] = s;
    __syncthreads();
    for (int off = 1; off < 1024; off <<= 1) {
        unsigned int u = (t >= off) ? bs[t - off] : 0u;
        __syncthreads();
        bs[t] += u;
        __syncthreads();
    }
    unsigned int base = rb + bs[t] - s;
    #pragma unroll
    for (int k = 0; k < 8; k++) lc[t * 8 + k] = base + v[k];
    __syncthreads();
    unsigned int* st_ = start + (size_t)bi * START_STRIDE + r0;
    #pragma unroll
    for (int q = 0; q < 8; q++)
        st_[q * 1024 + t] = lc[q * 1024 + t];
    if (r == 7 && t == 0)
        start[(size_t)bi * START_STRIDE + NG] = rtotal;
}

// ---------------- k4a: radix partition into 32 sub-range segments ----------------
__global__ __launch_bounds__(1024) void k4a_part(const unsigned short* __restrict__ pixarr,
                                                 unsigned int* __restrict__ gsc,
                                                 unsigned int* __restrict__ parts)
{
    extern __shared__ unsigned int dynA[];
    unsigned int* cur32 = dynA;
    unsigned int* res   = dynA + 32;
    unsigned int* lcnt  = dynA + 64;
    unsigned int* lbuck = dynA + 96;
    int t = threadIdx.x;
    unsigned int bi    = blockIdx.x & 31u;
    unsigned int chunk = blockIdx.x >> 5;
    if (t < 32) cur32[t] = 0;
    __syncthreads();
    const uint4* src = (const uint4*)(pixarr + ((size_t)bi << 19)) + (chunk << 12);
    unsigned int idx0 = chunk << 15;
    #pragma unroll
    for (int it = 0; it < 4; it++) {
        uint4 v = src[t + it * 1024];
        unsigned int base_idx = idx0 + (t + it * 1024) * 8;
        const unsigned int* vw = (const unsigned int*)&v;
        #pragma unroll
        for (int h = 0; h < 8; h++) {
            unsigned int pix = (h & 1) ? (vw[h >> 1] >> 16) : (vw[h >> 1] & 0xFFFFu);
            unsigned int sub = pix >> 11;
            unsigned int pv = ((pix & 0x7FFu) << 19) | (base_idx + h);
            unsigned int slot = atomicAdd(&cur32[sub], 1u);
            if (slot < CAP4A) {
                lbuck[sub * CAP4A + slot] = pv;
            } else {
                unsigned int gs = atomicAdd(&gsc[(bi << 5) | sub], 1u);
                parts[(size_t)((bi << 5) | sub) * PART_STRIDE + gs] = pv;
            }
        }
    }
    __syncthreads();
    if (t < 32) {
        unsigned int n = cur32[t];
        n = n < CAP4A ? n : CAP4A;
        lcnt[t] = n;
        res[t] = atomicAdd(&gsc[(bi << 5) | t], n);
    }
    __syncthreads();
    for (int s = 0; s < 32; s++) {
        unsigned int n = lcnt[s];
        unsigned int b0 = res[s];
        unsigned int* dst = parts + (size_t)((bi << 5) | s) * PART_STRIDE + b0;
        const unsigned int* sb = lbuck + s * CAP4A;
        for (unsigned int k = t; k < n; k += 1024) dst[k] = sb[k];
    }
}

// ---------------- k4b: LDS-staged counting sort from segment ----------------
__global__ __launch_bounds__(1024) void k4b_fill(const unsigned int* __restrict__ gsc,
                                                 const unsigned int* __restrict__ parts,
                                                 const unsigned int* __restrict__ start,
                                                 unsigned int* __restrict__ sorted)
{
    extern __shared__ unsigned int dynB[];
    unsigned int* cur = dynB;
    unsigned int* buf = dynB + K4BINS;
    int t = threadIdx.x;
    unsigned int bi  = blockIdx.x & 31u;
    unsigned int sub = blockIdx.x >> 5;
    unsigned int bin0 = sub * K4BINS;
    const unsigned int* stg = start + (size_t)bi * START_STRIDE;
    unsigned int base = stg[bin0];
    unsigned int end  = stg[bin0 + K4BINS];
    unsigned int size = end - base;
    unsigned int n = gsc[(bi << 5) | sub];
    const unsigned int* seg = parts + (size_t)((bi << 5) | sub) * PART_STRIDE;
    unsigned int* dstbase = sorted + (size_t)bi * SORT_STRIDE;

    if (size <= K4CAP) {
        #pragma unroll 2
        for (int k = t; k < K4BINS; k += 1024) cur[k] = stg[bin0 + k] - base;
        for (int k = t; k < (int)size; k += 1024) buf[k] = SENTINEL;
        __syncthreads();
        for (unsigned int k = t; k < n; k += 1024) {
            unsigned int pv = seg[k];
            unsigned int bin = pv >> 19;
            unsigned int slot = atomicAdd(&cur[bin], 1u);
            buf[slot] = (((pv >> 16) & 7u) << 27) | ((pv & 0x7FFFFu) << 6);
        }
        __syncthreads();
        uint4* gdst = (uint4*)(dstbase + base);
        const uint4* lsrc = (const uint4*)buf;
        int n4 = (int)(size >> 2);
        for (int k = t; k < n4; k += 1024) gdst[k] = lsrc[k];
    } else {
        #pragma unroll 2
        for (int k = t; k < K4BINS; k += 1024) cur[k] = stg[bin0 + k];
        __syncthreads();
        for (unsigned int k = t; k < n; k += 1024) {
            unsigned int pv = seg[k];
            unsigned int bin = pv >> 19;
            unsigned int slot = atomicAdd(&cur[bin], 1u);
            dstbase[slot] = (((pv >> 16) & 7u) << 27) | ((pv & 0x7FFFFu) << 6);
        }
        __syncthreads();
        for (int k = t; k < K4BINS; k += 1024) {
            unsigned int e = stg[bin0 + k + 1];
            for (unsigned int x = cur[k]; x < e; x++) dstbase[x] = SENTINEL;
        }
    }
}

// ---------------- kf_conv: feat[b] f32 -> bf16 slab (NT read, coalesced) ----------------
__global__ __launch_bounds__(256) void kf_conv(const float* __restrict__ src,
                                               ushort4* __restrict__ dst)
{
    unsigned int base = blockIdx.x * 1024 + threadIdx.x;
    #pragma unroll
    for (int k = 0; k < 4; k++) {
        unsigned int idx = base + k * 256;
        f32x4c v = __builtin_nontemporal_load((const f32x4c*)(src) + idx);
        ushort4 o;
        o.x = f2bf(v.x); o.y = f2bf(v.y); o.z = f2bf(v.z); o.w = f2bf(v.w);
        dst[idx] = o;
    }
}

// ---------------- b_gather: early descriptor chain + payload prefetch ----------------
__global__ __launch_bounds__(256, 4) void b_gather(
    const unsigned short* __restrict__ fb16,
    const unsigned short* __restrict__ pixarr,
    const unsigned int* __restrict__ start,
    const unsigned int* __restrict__ sorted,
    const float* __restrict__ Wlin,
    const float* __restrict__ blin,
    const float* __restrict__ At,
    float* __restrict__ out,
    int b)
{
    __shared__ float At9[NBI][16];
    int t = threadIdx.x;
    int c4 = t & 7;
    int grp = t >> 3;

    unsigned int bidx = blockIdx.x;
    unsigned int i  = bidx & 7u;
    unsigned int gc = bidx >> 3;
    unsigned int bi = ((unsigned int)b << 3) | i;
    unsigned int g0 = gc << 5;
    unsigned int g = g0 + grp;

    // ---- start the dependent chain ASAP: pix -> s0/e0 -> first payloads ----
    unsigned int pix = pixarr[(((bi << 3) | i) << 16) | g];
    const unsigned int* st = start + (size_t)bi * START_STRIDE;
    unsigned int s0 = st[pix];
    unsigned int e0 = st[pix + 1];
    const unsigned int* pl = sorted + (size_t)bi * SORT_STRIDE;
    u32x4 pa = __builtin_nontemporal_load((const u32x4*)(pl + s0));
    u32x4 pb = __builtin_nontemporal_load((const u32x4*)(pl + s0 + 4));

    // setup overlaps the loads above
    At9[t >> 3][t & 7] = At[t];
    At9[t >> 3][8 + (t & 7)] = 0.f;
    int l = t & 63;
    short8 bf0, bf1;
    #pragma unroll
    for (int j = 0; j < 8; j++) {
        int kk = (l >> 4) * 8 + j;
        bf0[j] = (short)f2bf(Wlin[kk * NC + (l & 15)]);
        bf1[j] = (short)f2bf(Wlin[kk * NC + 16 + (l & 15)]);
    }
    const char* fbB = (const char*)fb16;
    unsigned int cb = c4 << 3;
    __syncthreads();

    const float* Atrow = At9[bi];
    float ax = 0.f, ay = 0.f, az = 0.f, aw = 0.f, wsum = 0.f;
    for (unsigned int k0 = s0; k0 < e0; k0 += 8) {
        unsigned int pv[8] = {pa.x, pa.y, pa.z, pa.w, pb.x, pb.y, pb.z, pb.w};
        // issue row loads for current chunk
        uint2 uv[8];
        #pragma unroll
        for (int h = 0; h < 8; h++)
            uv[h] = *(const uint2*)(fbB + ((pv[h] & 0x01FFFFC0u) | cb));
        // prefetch next chunk's payloads before the FMAs
        if (k0 + 8 < e0) {
            pa = __builtin_nontemporal_load((const u32x4*)(pl + k0 + 8));
            pb = __builtin_nontemporal_load((const u32x4*)(pl + k0 + 12));
        }
        float wv[8];
        #pragma unroll
        for (int h = 0; h < 8; h++)
            wv[h] = Atrow[pv[h] >> 27];
        #pragma unroll
        for (int h = 0; h < 8; h++) {
            ax = fmaf(wv[h], __uint_as_float(uv[h].x << 16), ax);
            ay = fmaf(wv[h], __uint_as_float(uv[h].x & 0xFFFF0000u), ay);
            az = fmaf(wv[h], __uint_as_float(uv[h].y << 16), az);
            aw = fmaf(wv[h], __uint_as_float(uv[h].y & 0xFFFF0000u), aw);
            wsum += wv[h];
        }
    }

    // ---- wave-local MFMA epilogue ----
    int r = l & 15;
    int kb = l >> 4;
    int s0l = (((r & 7) << 3) | (kb << 1)) & 63;
    int s1l = s0l | 1;
    float v0x = __shfl(ax, s0l, 64), v0y = __shfl(ay, s0l, 64);
    float v0z = __shfl(az, s0l, 64), v0w = __shfl(aw, s0l, 64);
    float v1x = __shfl(ax, s1l, 64), v1y = __shfl(ay, s1l, 64);
    float v1z = __shfl(az, s1l, 64), v1w = __shfl(aw, s1l, 64);
    short8 af;
    if (r < 8) {
        af[0] = (short)f2bf(v0x); af[1] = (short)f2bf(v0y);
        af[2] = (short)f2bf(v0z); af[3] = (short)f2bf(v0w);
        af[4] = (short)f2bf(v1x); af[5] = (short)f2bf(v1y);
        af[6] = (short)f2bf(v1z); af[7] = (short)f2bf(v1w);
    } else {
        af = short8{0, 0, 0, 0, 0, 0, 0, 0};
    }
    float bias0 = blin[l & 15];
    float bias1 = blin[16 + (l & 15)];
    f32x4 c0, c1;
    #pragma unroll
    for (int q = 0; q < 4; q++) {
        int row = kb * 4 + q;
        float wvx = __shfl(wsum, (row << 3) & 63, 64);
        wvx = (row < 8) ? wvx : 0.f;
        c0[q] = bias0 * wvx;
        c1[q] = bias1 * wvx;
    }
    c0 = __builtin_amdgcn_mfma_f32_16x16x32_bf16(af, bf0, c0, 0, 0, 0);
    c1 = __builtin_amdgcn_mfma_f32_16x16x32_bf16(af, bf1, c1, 0, 0, 0);
    if (l < 32) {
        size_t rowbase = (((size_t)bi << 16) | g0) + (t >> 6) * 8;
        #pragma unroll
        for (int q = 0; q < 4; q++) {
            size_t rr = rowbase + (l >> 4) * 4 + q;
            __builtin_nontemporal_store(c0[q], &out[rr * NC + (l & 15)]);
            __builtin_nontemporal_store(c1[q], &out[rr * NC + 16 + (l & 15)]);
        }
    }
}

extern "C" void kernel_launch(void* const* d_in, const int* in_sizes, int n_in,
                              void* d_out, int out_size, void* d_ws, size_t ws_size,
                              hipStream_t stream)
{
    const float* features = (const float*)d_in[0];
    const float* xy       = (const float*)d_in[1];
    const float* ext      = (const float*)d_in[2];
    const float* Wlin     = (const float*)d_in[3];
    const float* blin     = (const float*)d_in[4];
    float* out = (float*)d_out;

    char* ws = (char*)d_ws;
    float*          At     = (float*)(ws + OFF_AT);
    unsigned int*   rtot   = (unsigned int*)(ws + OFF_RTOT);
    unsigned int*   gsc    = (unsigned int*)(ws + OFF_GSC);
    unsigned int*   start  = (unsigned int*)(ws + OFF_START);
    unsigned int*   cnt    = (unsigned int*)(ws + OFF_CNT);
    unsigned short* pixarr = (unsigned short*)(ws + OFF_PIX);
    unsigned int*   sorted = (unsigned int*)(ws + OFF_SORT);
    unsigned int*   parts  = (unsigned int*)(ws + OFF_PARTS);
    unsigned short* fb16   = (unsigned short*)(ws + OFF_FB16);

    static const size_t k4a_lds = (96 + 32 * CAP4A) * sizeof(unsigned int);
    static const size_t k4b_lds = (K4BINS + K4CAP) * sizeof(unsigned int);
    hipFuncSetAttribute((const void*)k4a_part,
                        hipFuncAttributeMaxDynamicSharedMemorySize, (int)k4a_lds);
    hipFuncSetAttribute((const void*)k4b_fill,
                        hipFuncAttributeMaxDynamicSharedMemorySize, (int)k4b_lds);

    k1_pix<<<16385, 256, 0, stream>>>((const float2*)xy, pixarr, ext,
                                      out + STACKED_ELEMS, At);
    k2_hist<<<NBI * RSPLIT, 1024, 0, stream>>>(pixarr, cnt, rtot);
    k3c_scan<<<NBI * RSPLIT, 1024, 0, stream>>>(cnt, rtot, start);

    hipMemsetAsync(gsc, 0, 1024 * sizeof(unsigned int), stream);
    k4a_part<<<NBI * 16, 1024, k4a_lds, stream>>>(pixarr, gsc, parts);
    k4b_fill<<<NBI * K4SPLIT, 1024, k4b_lds, stream>>>(gsc, parts, start, sorted);

    for (int b = 0; b < NB; b++) {
        const float* src = features + (((size_t)b) << 19) * NC;
        kf_conv<<<4096, 256, 0, stream>>>(src, (ushort4*)fb16);
        b_gather<<<16384, 256, 0, stream>>>(fb16, pixarr, start, sorted,
                                            Wlin, blin, At, out, b);
    }
}

// Round 27
// 580.512 us; speedup vs baseline: 1.3131x; 1.0200x over previous
//
#include <hip/hip_runtime.h>
#include <math.h>

#define NB 4
#define NV 8
#define NC 32
#define NG 65536
#define IMGW 256
#define NBI 32               // NB*NV
#define K4SPLIT 32           // sub-range split (2048 bins)
#define K4BINS (NG / K4SPLIT)
#define K4CAP 24576          // k4c LDS slot capacity (mean padded ~23.7K)
#define CAP4A 1272           // k4a per-bucket LDS capacity
#define PART_STRIDE 19456    // parts segment stride
#define START_STRIDE 65544
#define SORT_STRIDE (1u << 20)
#define SENTINEL (8u << 27)  // widx=8 (w=0); byte-row masks to 0

static constexpr long long STACKED_ELEMS = (long long)NB * NV * NG * NC; // 67108864

typedef __attribute__((ext_vector_type(8))) short short8;
typedef __attribute__((ext_vector_type(4))) float f32x4;
typedef __attribute__((ext_vector_type(4))) unsigned int u32x4;
typedef __attribute__((ext_vector_type(4))) float f32x4c;

// ---------------- ws layout ----------------
static constexpr size_t OFF_AT     = 0;          // 1 KB
static constexpr size_t OFF_PTOT   = 1024;       // 1024 u32
static constexpr size_t OFF_PBASE  = 5120;       // 1024 u32
static constexpr size_t OFF_GSC    = 9216;       // 1024 u32
static constexpr size_t OFF_START  = 16384;
static constexpr size_t OFF_LSTART = OFF_START + (size_t)NBI * START_STRIDE * 4;   // 8.4 MB
static constexpr size_t OFF_PIX    = OFF_LSTART + (size_t)1024 * K4BINS * 4;       // +8.4 MB
static constexpr size_t OFF_SORT   = OFF_PIX + (size_t)NBI * NV * NG * 2;          // +33.6 MB
static constexpr size_t OFF_FB16   = OFF_SORT + (size_t)NBI * SORT_STRIDE * 4;     // +134 MB
static constexpr size_t OFF_PARTS  = OFF_FB16;   // overlay: parts live only in sort phase

__device__ __forceinline__ unsigned short f2bf(float f)
{
    unsigned int u = __float_as_uint(f);
    return (unsigned short)((u + 0x7FFFu + ((u >> 16) & 1u)) >> 16);
}

// ---------------- k1: pixel precompute; last block computes adjacency ----------------
__global__ __launch_bounds__(256) void k1_pix(const float2* __restrict__ xy,
                                              unsigned short* __restrict__ pixarr,
                                              const float* __restrict__ ext,
                                              float* __restrict__ A_out,
                                              float* __restrict__ At_out)
{
    if (blockIdx.x == 16384) {
        __shared__ float ctr[NB * NV][3];
        __shared__ float Dsh[NB * NV * NV];
        int t = threadIdx.x;
        if (t < NB * NV) {
            const float* E = ext + t * 16;
            #pragma unroll
            for (int i = 0; i < 3; i++) {
                float s = E[0 * 4 + i] * E[0 * 4 + 3]
                        + E[1 * 4 + i] * E[1 * 4 + 3]
                        + E[2 * 4 + i] * E[2 * 4 + 3];
                ctr[t][i] = -s;
            }
        }
        __syncthreads();
        {
            int b = t >> 6, i = (t >> 3) & 7, j = t & 7;
            float dx = ctr[b * 8 + i][0] - ctr[b * 8 + j][0];
            float dy = ctr[b * 8 + i][1] - ctr[b * 8 + j][1];
            float dz = ctr[b * 8 + i][2] - ctr[b * 8 + j][2];
            Dsh[t] = dx * dx + dy * dy + dz * dz;
        }
        __syncthreads();
        if (t < NB * NV) {
            int ri = t & 7;
            const float* drow = &Dsh[t * 8];
            bool chosen[8] = {false, false, false, false, false, false, false, false};
            for (int n = 0; n < 3; n++) {
                int best = -1; float bs = -3.0e38f;
                for (int j2 = 0; j2 < 8; j2++) {
                    if (j2 == ri || chosen[j2]) continue;
                    float s = -drow[j2];
                    if (s > bs) { bs = s; best = j2; }
                }
                chosen[best] = true;
            }
            float row[8]; float deg = 0.f;
            #pragma unroll
            for (int j2 = 0; j2 < 8; j2++) {
                float a = 0.f;
                if (j2 == ri)        a = 1.0f;
                else if (chosen[j2]) a = 1.0f / (1.0f + sqrtf(drow[j2] + 1e-6f));
                row[j2] = a; deg += a;
            }
            float dn = deg + (deg == 0.f ? 1.f : 0.f);
            #pragma unroll
            for (int j2 = 0; j2 < 8; j2++) {
                A_out[t * 8 + j2]  = row[j2];
                At_out[t * 8 + j2] = row[j2] / dn;
            }
        }
        return;
    }
    unsigned int base = blockIdx.x * 1024 + threadIdx.x;
    #pragma unroll
    for (int k = 0; k < 4; k++) {
        unsigned int tid = base + k * 256; // [b][j][i][g]
        float2 p = xy[tid];
        float px = fminf(fmaxf(rintf(p.x), 0.f), (float)(IMGW - 1));
        float py = fminf(fmaxf(rintf(p.y), 0.f), (float)(IMGW - 1));
        unsigned int pix = (unsigned int)py * IMGW + (unsigned int)px;
        unsigned int g = tid & 0xFFFFu;
        unsigned int i = (tid >> 16) & 7u;
        unsigned int j = (tid >> 19) & 7u;
        unsigned int b = tid >> 22;
        unsigned int bi = (b << 3) | i;
        pixarr[(((bi << 3) | j) << 16) | g] = (unsigned short)pix; // [bi][j][g]
    }
}

// ---------------- k4a: radix partition into 32 sub-range segments ----------------
__global__ __launch_bounds__(1024) void k4a_part(const unsigned short* __restrict__ pixarr,
                                                 unsigned int* __restrict__ gsc,
                                                 unsigned int* __restrict__ parts)
{
    extern __shared__ unsigned int dynA[];
    unsigned int* cur32 = dynA;
    unsigned int* res   = dynA + 32;
    unsigned int* lcnt  = dynA + 64;
    unsigned int* lbuck = dynA + 96;
    int t = threadIdx.x;
    unsigned int bi    = blockIdx.x & 31u; // XCD = bi%8
    unsigned int chunk = blockIdx.x >> 5;
    if (t < 32) cur32[t] = 0;
    __syncthreads();
    const uint4* src = (const uint4*)(pixarr + ((size_t)bi << 19)) + (chunk << 12);
    unsigned int idx0 = chunk << 15;
    #pragma unroll
    for (int it = 0; it < 4; it++) {
        uint4 v = src[t + it * 1024];
        unsigned int base_idx = idx0 + (t + it * 1024) * 8;
        const unsigned int* vw = (const unsigned int*)&v;
        #pragma unroll
        for (int h = 0; h < 8; h++) {
            unsigned int pix = (h & 1) ? (vw[h >> 1] >> 16) : (vw[h >> 1] & 0xFFFFu);
            unsigned int sub = pix >> 11;
            unsigned int pv = ((pix & 0x7FFu) << 19) | (base_idx + h);
            unsigned int slot = atomicAdd(&cur32[sub], 1u);
            if (slot < CAP4A) {
                lbuck[sub * CAP4A + slot] = pv;
            } else {
                unsigned int gs = atomicAdd(&gsc[(bi << 5) | sub], 1u);
                parts[(size_t)((bi << 5) | sub) * PART_STRIDE + gs] = pv;
            }
        }
    }
    __syncthreads();
    if (t < 32) {
        unsigned int n = cur32[t];
        n = n < CAP4A ? n : CAP4A;
        lcnt[t] = n;
        res[t] = atomicAdd(&gsc[(bi << 5) | t], n);
    }
    __syncthreads();
    for (int s = 0; s < 32; s++) {
        unsigned int n = lcnt[s];
        unsigned int b0 = res[s];
        unsigned int* dst = parts + (size_t)((bi << 5) | s) * PART_STRIDE + b0;
        const unsigned int* sb = lbuck + s * CAP4A;
        for (unsigned int k = t; k < n; k += 1024) dst[k] = sb[k];
    }
}

// ---------------- k4h: per-segment histogram + padded local scan ----------------
// blk = (sub<<5)|bi layout matches k4a/k4c. Writes lstart[blk][2048] + ptot[blk].
__global__ __launch_bounds__(1024) void k4h_hist(const unsigned int* __restrict__ gsc,
                                                 const unsigned int* __restrict__ parts,
                                                 unsigned int* __restrict__ lstart,
                                                 unsigned int* __restrict__ ptot)
{
    __shared__ unsigned int hist[K4BINS]; // 2048
    __shared__ unsigned int bs[1024];
    int t = threadIdx.x;
    unsigned int bi  = blockIdx.x & 31u;
    unsigned int sub = blockIdx.x >> 5;
    unsigned int n = gsc[(bi << 5) | sub];
    const unsigned int* seg = parts + (size_t)((bi << 5) | sub) * PART_STRIDE;
    hist[t] = 0; hist[t + 1024] = 0;
    __syncthreads();
    for (unsigned int k = t; k < n; k += 1024)
        atomicAdd(&hist[seg[k] >> 19], 1u);
    __syncthreads();
    unsigned int c0 = (hist[2 * t] + 7u) & ~7u;
    unsigned int c1 = (hist[2 * t + 1] + 7u) & ~7u;
    unsigned int s = c0 + c1;
    bs[t] = s;
    __syncthreads();
    for (int off = 1; off < 1024; off <<= 1) {
        unsigned int u = (t >= off) ? bs[t - off] : 0u;
        __syncthreads();
        bs[t] += u;
        __syncthreads();
    }
    unsigned int base = bs[t] - s; // exclusive
    __syncthreads();
    hist[2 * t] = base;
    hist[2 * t + 1] = base + c0;
    __syncthreads();
    unsigned int* ls = lstart + (size_t)blockIdx.x * K4BINS;
    ls[t] = hist[t]; ls[t + 1024] = hist[t + 1024];
    if (t == 1023) ptot[blockIdx.x] = bs[1023];
}

// ---------------- k4s: per-bi prefix over 32 sub-totals ----------------
__global__ __launch_bounds__(64) void k4s_scan(const unsigned int* __restrict__ ptot,
                                               unsigned int* __restrict__ pbase,
                                               unsigned int* __restrict__ start)
{
    int t = threadIdx.x;
    if (t < 32) {
        unsigned int run = 0;
        #pragma unroll
        for (int q = 0; q < 32; q++) {
            pbase[(q << 5) | t] = run;
            run += ptot[(q << 5) | t];
        }
        start[(size_t)t * START_STRIDE + NG] = run; // sentinel
    }
}

// ---------------- k4c: LDS-staged fill + flush; writes start[] ----------------
__global__ __launch_bounds__(1024) void k4c_fill(const unsigned int* __restrict__ gsc,
                                                 const unsigned int* __restrict__ parts,
                                                 const unsigned int* __restrict__ lstart,
                                                 const unsigned int* __restrict__ pbase,
                                                 const unsigned int* __restrict__ ptot,
                                                 unsigned int* __restrict__ sorted,
                                                 unsigned int* __restrict__ start)
{
    extern __shared__ unsigned int dynB[];
    unsigned int* cur = dynB;          // 2048 relative cursors
    unsigned int* buf = dynB + K4BINS; // K4CAP payload slots
    int t = threadIdx.x;
    unsigned int bi  = blockIdx.x & 31u;
    unsigned int sub = blockIdx.x >> 5;
    unsigned int n = gsc[(bi << 5) | sub];
    unsigned int base = pbase[(sub << 5) | bi];
    unsigned int size = ptot[(sub << 5) | bi];
    const unsigned int* ls = lstart + (size_t)((sub << 5) | bi) * K4BINS;
    const unsigned int* seg = parts + (size_t)((bi << 5) | sub) * PART_STRIDE;
    unsigned int* dstbase = sorted + (size_t)bi * SORT_STRIDE;
    unsigned int* stw = start + (size_t)bi * START_STRIDE + sub * K4BINS;

    // write start[] (coalesced) and load cursors
    #pragma unroll 2
    for (int k = t; k < K4BINS; k += 1024) {
        unsigned int v = ls[k];
        stw[k] = base + v;
        cur[k] = v;
    }

    if (size <= K4CAP) {
        for (int k = t; k < (int)size; k += 1024) buf[k] = SENTINEL;
        __syncthreads();
        for (unsigned int k = t; k < n; k += 1024) {
            unsigned int pv = seg[k];
            unsigned int bin = pv >> 19;
            unsigned int slot = atomicAdd(&cur[bin], 1u);
            buf[slot] = (((pv >> 16) & 7u) << 27) | ((pv & 0x7FFFFu) << 6);
        }
        __syncthreads();
        uint4* gdst = (uint4*)(dstbase + base);
        const uint4* lsrc = (const uint4*)buf;
        int n4 = (int)(size >> 2);
        for (int k = t; k < n4; k += 1024) gdst[k] = lsrc[k];
    } else {
        __syncthreads();
        for (unsigned int k = t; k < n; k += 1024) {
            unsigned int pv = seg[k];
            unsigned int bin = pv >> 19;
            unsigned int slot = atomicAdd(&cur[bin], 1u);
            dstbase[base + slot] = (((pv >> 16) & 7u) << 27) | ((pv & 0x7FFFFu) << 6);
        }
        __syncthreads();
        for (int k = t; k < K4BINS; k += 1024) {
            unsigned int e = (k < K4BINS - 1) ? ls[k + 1] : size;
            for (unsigned int x = cur[k]; x < e; x++) dstbase[base + x] = SENTINEL;
        }
    }
}

// ---------------- kf_conv: feat[b] f32 -> bf16 slab (NT read, coalesced) ----------------
__global__ __launch_bounds__(256) void kf_conv(const float* __restrict__ src,
                                               ushort4* __restrict__ dst)
{
    unsigned int base = blockIdx.x * 1024 + threadIdx.x;
    #pragma unroll
    for (int k = 0; k < 4; k++) {
        unsigned int idx = base + k * 256;
        f32x4c v = __builtin_nontemporal_load((const f32x4c*)(src) + idx);
        ushort4 o;
        o.x = f2bf(v.x); o.y = f2bf(v.y); o.z = f2bf(v.z); o.w = f2bf(v.w);
        dst[idx] = o;
    }
}

// ---------------- b_gather: early descriptor chain + payload prefetch ----------------
__global__ __launch_bounds__(256, 4) void b_gather(
    const unsigned short* __restrict__ fb16,
    const unsigned short* __restrict__ pixarr,
    const unsigned int* __restrict__ start,
    const unsigned int* __restrict__ sorted,
    const float* __restrict__ Wlin,
    const float* __restrict__ blin,
    const float* __restrict__ At,
    float* __restrict__ out,
    int b)
{
    __shared__ float At9[NBI][16];
    int t = threadIdx.x;
    int c4 = t & 7;
    int grp = t >> 3;

    unsigned int bidx = blockIdx.x;
    unsigned int i  = bidx & 7u;
    unsigned int gc = bidx >> 3;
    unsigned int bi = ((unsigned int)b << 3) | i;
    unsigned int g0 = gc << 5;
    unsigned int g = g0 + grp;

    unsigned int pix = pixarr[(((bi << 3) | i) << 16) | g];
    const unsigned int* st = start + (size_t)bi * START_STRIDE;
    unsigned int s0 = st[pix];
    unsigned int e0 = st[pix + 1];
    const unsigned int* pl = sorted + (size_t)bi * SORT_STRIDE;
    u32x4 pa = __builtin_nontemporal_load((const u32x4*)(pl + s0));
    u32x4 pb = __builtin_nontemporal_load((const u32x4*)(pl + s0 + 4));

    At9[t >> 3][t & 7] = At[t];
    At9[t >> 3][8 + (t & 7)] = 0.f;
    int l = t & 63;
    short8 bf0, bf1;
    #pragma unroll
    for (int j = 0; j < 8; j++) {
        int kk = (l >> 4) * 8 + j;
        bf0[j] = (short)f2bf(Wlin[kk * NC + (l & 15)]);
        bf1[j] = (short)f2bf(Wlin[kk * NC + 16 + (l & 15)]);
    }
    const char* fbB = (const char*)fb16;
    unsigned int cb = c4 << 3;
    __syncthreads();

    const float* Atrow = At9[bi];
    float ax = 0.f, ay = 0.f, az = 0.f, aw = 0.f, wsum = 0.f;
    for (unsigned int k0 = s0; k0 < e0; k0 += 8) {
        unsigned int pv[8] = {pa.x, pa.y, pa.z, pa.w, pb.x, pb.y, pb.z, pb.w};
        uint2 uv[8];
        #pragma unroll
        for (int h = 0; h < 8; h++)
            uv[h] = *(const uint2*)(fbB + ((pv[h] & 0x01FFFFC0u) | cb));
        if (k0 + 8 < e0) {
            pa = __builtin_nontemporal_load((const u32x4*)(pl + k0 + 8));
            pb = __builtin_nontemporal_load((const u32x4*)(pl + k0 + 12));
        }
        float wv[8];
        #pragma unroll
        for (int h = 0; h < 8; h++)
            wv[h] = Atrow[pv[h] >> 27];
        #pragma unroll
        for (int h = 0; h < 8; h++) {
            ax = fmaf(wv[h], __uint_as_float(uv[h].x << 16), ax);
            ay = fmaf(wv[h], __uint_as_float(uv[h].x & 0xFFFF0000u), ay);
            az = fmaf(wv[h], __uint_as_float(uv[h].y << 16), az);
            aw = fmaf(wv[h], __uint_as_float(uv[h].y & 0xFFFF0000u), aw);
            wsum += wv[h];
        }
    }

    int r = l & 15;
    int kb = l >> 4;
    int s0l = (((r & 7) << 3) | (kb << 1)) & 63;
    int s1l = s0l | 1;
    float v0x = __shfl(ax, s0l, 64), v0y = __shfl(ay, s0l, 64);
    float v0z = __shfl(az, s0l, 64), v0w = __shfl(aw, s0l, 64);
    float v1x = __shfl(ax, s1l, 64), v1y = __shfl(ay, s1l, 64);
    float v1z = __shfl(az, s1l, 64), v1w = __shfl(aw, s1l, 64);
    short8 af;
    if (r < 8) {
        af[0] = (short)f2bf(v0x); af[1] = (short)f2bf(v0y);
        af[2] = (short)f2bf(v0z); af[3] = (short)f2bf(v0w);
        af[4] = (short)f2bf(v1x); af[5] = (short)f2bf(v1y);
        af[6] = (short)f2bf(v1z); af[7] = (short)f2bf(v1w);
    } else {
        af = short8{0, 0, 0, 0, 0, 0, 0, 0};
    }
    float bias0 = blin[l & 15];
    float bias1 = blin[16 + (l & 15)];
    f32x4 c0, c1;
    #pragma unroll
    for (int q = 0; q < 4; q++) {
        int row = kb * 4 + q;
        float wvx = __shfl(wsum, (row << 3) & 63, 64);
        wvx = (row < 8) ? wvx : 0.f;
        c0[q] = bias0 * wvx;
        c1[q] = bias1 * wvx;
    }
    c0 = __builtin_amdgcn_mfma_f32_16x16x32_bf16(af, bf0, c0, 0, 0, 0);
    c1 = __builtin_amdgcn_mfma_f32_16x16x32_bf16(af, bf1, c1, 0, 0, 0);
    if (l < 32) {
        size_t rowbase = (((size_t)bi << 16) | g0) + (t >> 6) * 8;
        #pragma unroll
        for (int q = 0; q < 4; q++) {
            size_t rr = rowbase + (l >> 4) * 4 + q;
            __builtin_nontemporal_store(c0[q], &out[rr * NC + (l & 15)]);
            __builtin_nontemporal_store(c1[q], &out[rr * NC + 16 + (l & 15)]);
        }
    }
}

extern "C" void kernel_launch(void* const* d_in, const int* in_sizes, int n_in,
                              void* d_out, int out_size, void* d_ws, size_t ws_size,
                              hipStream_t stream)
{
    const float* features = (const float*)d_in[0];
    const float* xy       = (const float*)d_in[1];
    const float* ext      = (const float*)d_in[2];
    const float* Wlin     = (const float*)d_in[3];
    const float* blin     = (const float*)d_in[4];
    float* out = (float*)d_out;

    char* ws = (char*)d_ws;
    float*          At     = (float*)(ws + OFF_AT);
    unsigned int*   ptot   = (unsigned int*)(ws + OFF_PTOT);
    unsigned int*   pbase  = (unsigned int*)(ws + OFF_PBASE);
    unsigned int*   gsc    = (unsigned int*)(ws + OFF_GSC);
    unsigned int*   start  = (unsigned int*)(ws + OFF_START);
    unsigned int*   lstart = (unsigned int*)(ws + OFF_LSTART);
    unsigned short* pixarr = (unsigned short*)(ws + OFF_PIX);
    unsigned int*   sorted = (unsigned int*)(ws + OFF_SORT);
    unsigned int*   parts  = (unsigned int*)(ws + OFF_PARTS);
    unsigned short* fb16   = (unsigned short*)(ws + OFF_FB16);

    static const size_t k4a_lds = (96 + 32 * CAP4A) * sizeof(unsigned int);
    static const size_t k4c_lds = (K4BINS + K4CAP) * sizeof(unsigned int);
    hipFuncSetAttribute((const void*)k4a_part,
                        hipFuncAttributeMaxDynamicSharedMemorySize, (int)k4a_lds);
    hipFuncSetAttribute((const void*)k4c_fill,
                        hipFuncAttributeMaxDynamicSharedMemorySize, (int)k4c_lds);

    k1_pix<<<16385, 256, 0, stream>>>((const float2*)xy, pixarr, ext,
                                      out + STACKED_ELEMS, At);

    hipMemsetAsync(gsc, 0, 1024 * sizeof(unsigned int), stream);
    k4a_part<<<NBI * 16, 1024, k4a_lds, stream>>>(pixarr, gsc, parts);
    k4h_hist<<<1024, 1024, 0, stream>>>(gsc, parts, lstart, ptot);
    k4s_scan<<<1, 64, 0, stream>>>(ptot, pbase, start);
    k4c_fill<<<1024, 1024, k4c_lds, stream>>>(gsc, parts, lstart, pbase, ptot,
                                              sorted, start);

    for (int b = 0; b < NB; b++) {
        const float* src = features + (((size_t)b) << 19) * NC;
        kf_conv<<<4096, 256, 0, stream>>>(src, (ushort4*)fb16);
        b_gather<<<16384, 256, 0, stream>>>(fb16, pixarr, start, sorted,
                                            Wlin, blin, At, out, b);
    }
}

// Round 28
// 567.660 us; speedup vs baseline: 1.3429x; 1.0226x over previous
//
#include <hip/hip_runtime.h>
#include <math.h>

#define NB 4
#define NV 8
#define NC 32
#define NG 65536
#define IMGW 256
#define NBI 32               // NB*NV
#define K4SPLIT 32           // sub-range split (2048 bins)
#define K4BINS (NG / K4SPLIT)
#define K4CAP 24576          // k4c LDS slot capacity (mean padded ~23.7K)
#define CAP4A 1272           // k4a per-bucket LDS capacity
#define PART_STRIDE 19456    // parts segment stride
#define START_STRIDE 65544
#define SORT_STRIDE (1u << 20)
#define SENTINEL (8u << 27)  // widx=8 (w=0); byte-row masks to 0

static constexpr long long STACKED_ELEMS = (long long)NB * NV * NG * NC; // 67108864

typedef __attribute__((ext_vector_type(8))) short short8;
typedef __attribute__((ext_vector_type(4))) float f32x4;
typedef __attribute__((ext_vector_type(4))) unsigned int u32x4;
typedef __attribute__((ext_vector_type(4))) float f32x4c;

// ---------------- ws layout ----------------
static constexpr size_t OFF_AT     = 0;          // 1 KB
static constexpr size_t OFF_PTOT   = 1024;       // 1024 u32
static constexpr size_t OFF_PBASE  = 5120;       // 1024 u32
static constexpr size_t OFF_GSC    = 9216;       // 1024 u32
static constexpr size_t OFF_START  = 16384;
static constexpr size_t OFF_LSTART = OFF_START + (size_t)NBI * START_STRIDE * 4;   // 8.4 MB
static constexpr size_t OFF_PIX    = OFF_LSTART + (size_t)1024 * K4BINS * 4;       // +8.4 MB
static constexpr size_t OFF_SORT   = OFF_PIX + (size_t)NBI * NV * NG * 2;          // +33.6 MB
static constexpr size_t OFF_FB16   = OFF_SORT + (size_t)NBI * SORT_STRIDE * 4;     // 184.6 MB
static constexpr size_t OFF_PARTS  = OFF_FB16;   // overlay: parts live only in sort phase
// peak: max(OFF_PARTS + 79.7 MB = 264.3 MB, OFF_FB16 + 67.1 MB = 251.7 MB) < 268.4 MB proven

__device__ __forceinline__ unsigned short f2bf(float f)
{
    unsigned int u = __float_as_uint(f);
    return (unsigned short)((u + 0x7FFFu + ((u >> 16) & 1u)) >> 16);
}

// ---------------- k1: pixel precompute; last block computes adjacency ----------------
__global__ __launch_bounds__(256) void k1_pix(const float2* __restrict__ xy,
                                              unsigned short* __restrict__ pixarr,
                                              const float* __restrict__ ext,
                                              float* __restrict__ A_out,
                                              float* __restrict__ At_out)
{
    if (blockIdx.x == 16384) {
        __shared__ float ctr[NB * NV][3];
        __shared__ float Dsh[NB * NV * NV];
        int t = threadIdx.x;
        if (t < NB * NV) {
            const float* E = ext + t * 16;
            #pragma unroll
            for (int i = 0; i < 3; i++) {
                float s = E[0 * 4 + i] * E[0 * 4 + 3]
                        + E[1 * 4 + i] * E[1 * 4 + 3]
                        + E[2 * 4 + i] * E[2 * 4 + 3];
                ctr[t][i] = -s;
            }
        }
        __syncthreads();
        {
            int b = t >> 6, i = (t >> 3) & 7, j = t & 7;
            float dx = ctr[b * 8 + i][0] - ctr[b * 8 + j][0];
            float dy = ctr[b * 8 + i][1] - ctr[b * 8 + j][1];
            float dz = ctr[b * 8 + i][2] - ctr[b * 8 + j][2];
            Dsh[t] = dx * dx + dy * dy + dz * dz;
        }
        __syncthreads();
        if (t < NB * NV) {
            int ri = t & 7;
            const float* drow = &Dsh[t * 8];
            bool chosen[8] = {false, false, false, false, false, false, false, false};
            for (int n = 0; n < 3; n++) {
                int best = -1; float bs = -3.0e38f;
                for (int j2 = 0; j2 < 8; j2++) {
                    if (j2 == ri || chosen[j2]) continue;
                    float s = -drow[j2];
                    if (s > bs) { bs = s; best = j2; }
                }
                chosen[best] = true;
            }
            float row[8]; float deg = 0.f;
            #pragma unroll
            for (int j2 = 0; j2 < 8; j2++) {
                float a = 0.f;
                if (j2 == ri)        a = 1.0f;
                else if (chosen[j2]) a = 1.0f / (1.0f + sqrtf(drow[j2] + 1e-6f));
                row[j2] = a; deg += a;
            }
            float dn = deg + (deg == 0.f ? 1.f : 0.f);
            #pragma unroll
            for (int j2 = 0; j2 < 8; j2++) {
                A_out[t * 8 + j2]  = row[j2];
                At_out[t * 8 + j2] = row[j2] / dn;
            }
        }
        return;
    }
    unsigned int base = blockIdx.x * 1024 + threadIdx.x;
    #pragma unroll
    for (int k = 0; k < 4; k++) {
        unsigned int tid = base + k * 256; // [b][j][i][g]
        float2 p = xy[tid];
        float px = fminf(fmaxf(rintf(p.x), 0.f), (float)(IMGW - 1));
        float py = fminf(fmaxf(rintf(p.y), 0.f), (float)(IMGW - 1));
        unsigned int pix = (unsigned int)py * IMGW + (unsigned int)px;
        unsigned int g = tid & 0xFFFFu;
        unsigned int i = (tid >> 16) & 7u;
        unsigned int j = (tid >> 19) & 7u;
        unsigned int b = tid >> 22;
        unsigned int bi = (b << 3) | i;
        pixarr[(((bi << 3) | j) << 16) | g] = (unsigned short)pix; // [bi][j][g]
    }
}

// ---------------- k4a: radix partition into 32 sub-range segments ----------------
__global__ __launch_bounds__(1024) void k4a_part(const unsigned short* __restrict__ pixarr,
                                                 unsigned int* __restrict__ gsc,
                                                 unsigned int* __restrict__ parts)
{
    extern __shared__ unsigned int dynA[];
    unsigned int* cur32 = dynA;
    unsigned int* res   = dynA + 32;
    unsigned int* lcnt  = dynA + 64;
    unsigned int* lbuck = dynA + 96;
    int t = threadIdx.x;
    unsigned int bi    = blockIdx.x & 31u; // XCD = bi%8
    unsigned int chunk = blockIdx.x >> 5;
    if (t < 32) cur32[t] = 0;
    __syncthreads();
    const uint4* src = (const uint4*)(pixarr + ((size_t)bi << 19)) + (chunk << 12);
    unsigned int idx0 = chunk << 15;
    #pragma unroll
    for (int it = 0; it < 4; it++) {
        uint4 v = src[t + it * 1024];
        unsigned int base_idx = idx0 + (t + it * 1024) * 8;
        const unsigned int* vw = (const unsigned int*)&v;
        #pragma unroll
        for (int h = 0; h < 8; h++) {
            unsigned int pix = (h & 1) ? (vw[h >> 1] >> 16) : (vw[h >> 1] & 0xFFFFu);
            unsigned int sub = pix >> 11;
            unsigned int pv = ((pix & 0x7FFu) << 19) | (base_idx + h);
            unsigned int slot = atomicAdd(&cur32[sub], 1u);
            if (slot < CAP4A) {
                lbuck[sub * CAP4A + slot] = pv;
            } else {
                unsigned int gs = atomicAdd(&gsc[(bi << 5) | sub], 1u);
                parts[(size_t)((bi << 5) | sub) * PART_STRIDE + gs] = pv;
            }
        }
    }
    __syncthreads();
    if (t < 32) {
        unsigned int n = cur32[t];
        n = n < CAP4A ? n : CAP4A;
        lcnt[t] = n;
        res[t] = atomicAdd(&gsc[(bi << 5) | t], n);
    }
    __syncthreads();
    for (int s = 0; s < 32; s++) {
        unsigned int n = lcnt[s];
        unsigned int b0 = res[s];
        unsigned int* dst = parts + (size_t)((bi << 5) | s) * PART_STRIDE + b0;
        const unsigned int* sb = lbuck + s * CAP4A;
        for (unsigned int k = t; k < n; k += 1024) dst[k] = sb[k];
    }
}

// ---------------- k4h: per-segment histogram + padded local scan ----------------
__global__ __launch_bounds__(1024) void k4h_hist(const unsigned int* __restrict__ gsc,
                                                 const unsigned int* __restrict__ parts,
                                                 unsigned int* __restrict__ lstart,
                                                 unsigned int* __restrict__ ptot)
{
    __shared__ unsigned int hist[K4BINS]; // 2048
    __shared__ unsigned int bs[1024];
    int t = threadIdx.x;
    unsigned int bi  = blockIdx.x & 31u;
    unsigned int sub = blockIdx.x >> 5;
    unsigned int n = gsc[(bi << 5) | sub];
    const unsigned int* seg = parts + (size_t)((bi << 5) | sub) * PART_STRIDE;
    hist[t] = 0; hist[t + 1024] = 0;
    __syncthreads();
    for (unsigned int k = t; k < n; k += 1024)
        atomicAdd(&hist[seg[k] >> 19], 1u);
    __syncthreads();
    unsigned int c0 = (hist[2 * t] + 7u) & ~7u;
    unsigned int c1 = (hist[2 * t + 1] + 7u) & ~7u;
    unsigned int s = c0 + c1;
    bs[t] = s;
    __syncthreads();
    for (int off = 1; off < 1024; off <<= 1) {
        unsigned int u = (t >= off) ? bs[t - off] : 0u;
        __syncthreads();
        bs[t] += u;
        __syncthreads();
    }
    unsigned int base = bs[t] - s; // exclusive
    __syncthreads();
    hist[2 * t] = base;
    hist[2 * t + 1] = base + c0;
    __syncthreads();
    unsigned int* ls = lstart + (size_t)blockIdx.x * K4BINS;
    ls[t] = hist[t]; ls[t + 1024] = hist[t + 1024];
    if (t == 1023) ptot[blockIdx.x] = bs[1023];
}

// ---------------- k4s: per-bi prefix over 32 sub-totals ----------------
__global__ __launch_bounds__(64) void k4s_scan(const unsigned int* __restrict__ ptot,
                                               unsigned int* __restrict__ pbase,
                                               unsigned int* __restrict__ start)
{
    int t = threadIdx.x;
    if (t < 32) {
        unsigned int run = 0;
        #pragma unroll
        for (int q = 0; q < 32; q++) {
            pbase[(q << 5) | t] = run;
            run += ptot[(q << 5) | t];
        }
        start[(size_t)t * START_STRIDE + NG] = run; // sentinel
    }
}

// ---------------- k4c: LDS-staged fill + flush; writes start[] ----------------
__global__ __launch_bounds__(1024) void k4c_fill(const unsigned int* __restrict__ gsc,
                                                 const unsigned int* __restrict__ parts,
                                                 const unsigned int* __restrict__ lstart,
                                                 const unsigned int* __restrict__ pbase,
                                                 const unsigned int* __restrict__ ptot,
                                                 unsigned int* __restrict__ sorted,
                                                 unsigned int* __restrict__ start)
{
    extern __shared__ unsigned int dynB[];
    unsigned int* cur = dynB;          // 2048 relative cursors
    unsigned int* buf = dynB + K4BINS; // K4CAP payload slots
    int t = threadIdx.x;
    unsigned int bi  = blockIdx.x & 31u;
    unsigned int sub = blockIdx.x >> 5;
    unsigned int n = gsc[(bi << 5) | sub];
    unsigned int base = pbase[(sub << 5) | bi];
    unsigned int size = ptot[(sub << 5) | bi];
    const unsigned int* ls = lstart + (size_t)((sub << 5) | bi) * K4BINS;
    const unsigned int* seg = parts + (size_t)((bi << 5) | sub) * PART_STRIDE;
    unsigned int* dstbase = sorted + (size_t)bi * SORT_STRIDE;
    unsigned int* stw = start + (size_t)bi * START_STRIDE + sub * K4BINS;

    #pragma unroll 2
    for (int k = t; k < K4BINS; k += 1024) {
        unsigned int v = ls[k];
        stw[k] = base + v;
        cur[k] = v;
    }

    if (size <= K4CAP) {
        for (int k = t; k < (int)size; k += 1024) buf[k] = SENTINEL;
        __syncthreads();
        for (unsigned int k = t; k < n; k += 1024) {
            unsigned int pv = seg[k];
            unsigned int bin = pv >> 19;
            unsigned int slot = atomicAdd(&cur[bin], 1u);
            buf[slot] = (((pv >> 16) & 7u) << 27) | ((pv & 0x7FFFFu) << 6);
        }
        __syncthreads();
        uint4* gdst = (uint4*)(dstbase + base);
        const uint4* lsrc = (const uint4*)buf;
        int n4 = (int)(size >> 2);
        for (int k = t; k < n4; k += 1024) gdst[k] = lsrc[k];
    } else {
        __syncthreads();
        for (unsigned int k = t; k < n; k += 1024) {
            unsigned int pv = seg[k];
            unsigned int bin = pv >> 19;
            unsigned int slot = atomicAdd(&cur[bin], 1u);
            dstbase[base + slot] = (((pv >> 16) & 7u) << 27) | ((pv & 0x7FFFFu) << 6);
        }
        __syncthreads();
        for (int k = t; k < K4BINS; k += 1024) {
            unsigned int e = (k < K4BINS - 1) ? ls[k + 1] : size;
            for (unsigned int x = cur[k]; x < e; x++) dstbase[base + x] = SENTINEL;
        }
    }
}

// ---------------- kf_conv: 2 b-slabs f32 -> bf16 (NT read, coalesced) ----------------
__global__ __launch_bounds__(256) void kf_conv(const float* __restrict__ src,
                                               ushort4* __restrict__ dst)
{
    unsigned int base = blockIdx.x * 1024 + threadIdx.x; // 8192 blocks x 4 float4
    #pragma unroll
    for (int k = 0; k < 4; k++) {
        unsigned int idx = base + k * 256;
        f32x4c v = __builtin_nontemporal_load((const f32x4c*)(src) + idx);
        ushort4 o;
        o.x = f2bf(v.x); o.y = f2bf(v.y); o.z = f2bf(v.z); o.w = f2bf(v.w);
        dst[idx] = o;
    }
}

// ---------------- b_gather: 2 b's per launch; early chain + prefetch; MFMA epilogue ----------------
__global__ __launch_bounds__(256, 4) void b_gather(
    const unsigned short* __restrict__ fb16,   // 2-slab buffer (b0, b0+1)
    const unsigned short* __restrict__ pixarr,
    const unsigned int* __restrict__ start,
    const unsigned int* __restrict__ sorted,
    const float* __restrict__ Wlin,
    const float* __restrict__ blin,
    const float* __restrict__ At,
    float* __restrict__ out,
    int b0)
{
    __shared__ float At9[NBI][16];
    int t = threadIdx.x;
    int c4 = t & 7;
    int grp = t >> 3;

    unsigned int bidx = blockIdx.x;
    unsigned int i  = bidx & 7u;               // XCD-pinned view
    unsigned int gc = (bidx >> 3) & 2047u;
    unsigned int db = bidx >> 14;              // 0 or 1: which b of the pair
    unsigned int bi = ((unsigned int)(b0 + db) << 3) | i;
    unsigned int g0 = gc << 5;
    unsigned int g = g0 + grp;

    // ---- start the dependent chain ASAP ----
    unsigned int pix = pixarr[(((bi << 3) | i) << 16) | g];
    const unsigned int* st = start + (size_t)bi * START_STRIDE;
    unsigned int s0 = st[pix];
    unsigned int e0 = st[pix + 1];
    const unsigned int* pl = sorted + (size_t)bi * SORT_STRIDE;
    u32x4 pa = __builtin_nontemporal_load((const u32x4*)(pl + s0));
    u32x4 pb = __builtin_nontemporal_load((const u32x4*)(pl + s0 + 4));

    At9[t >> 3][t & 7] = At[t];
    At9[t >> 3][8 + (t & 7)] = 0.f;
    int l = t & 63;
    short8 bf0, bf1;
    #pragma unroll
    for (int j = 0; j < 8; j++) {
        int kk = (l >> 4) * 8 + j;
        bf0[j] = (short)f2bf(Wlin[kk * NC + (l & 15)]);
        bf1[j] = (short)f2bf(Wlin[kk * NC + 16 + (l & 15)]);
    }
    const char* fbB = (const char*)fb16 + ((size_t)db << 25); // 33.55 MB per slab
    unsigned int cb = c4 << 3;
    __syncthreads();

    const float* Atrow = At9[bi];
    float ax = 0.f, ay = 0.f, az = 0.f, aw = 0.f, wsum = 0.f;
    for (unsigned int k0 = s0; k0 < e0; k0 += 8) {
        unsigned int pv[8] = {pa.x, pa.y, pa.z, pa.w, pb.x, pb.y, pb.z, pb.w};
        uint2 uv[8];
        #pragma unroll
        for (int h = 0; h < 8; h++)
            uv[h] = *(const uint2*)(fbB + ((pv[h] & 0x01FFFFC0u) | cb));
        if (k0 + 8 < e0) {
            pa = __builtin_nontemporal_load((const u32x4*)(pl + k0 + 8));
            pb = __builtin_nontemporal_load((const u32x4*)(pl + k0 + 12));
        }
        float wv[8];
        #pragma unroll
        for (int h = 0; h < 8; h++)
            wv[h] = Atrow[pv[h] >> 27];
        #pragma unroll
        for (int h = 0; h < 8; h++) {
            ax = fmaf(wv[h], __uint_as_float(uv[h].x << 16), ax);
            ay = fmaf(wv[h], __uint_as_float(uv[h].x & 0xFFFF0000u), ay);
            az = fmaf(wv[h], __uint_as_float(uv[h].y << 16), az);
            aw = fmaf(wv[h], __uint_as_float(uv[h].y & 0xFFFF0000u), aw);
            wsum += wv[h];
        }
    }

    // ---- wave-local MFMA epilogue ----
    int r = l & 15;
    int kb = l >> 4;
    int s0l = (((r & 7) << 3) | (kb << 1)) & 63;
    int s1l = s0l | 1;
    float v0x = __shfl(ax, s0l, 64), v0y = __shfl(ay, s0l, 64);
    float v0z = __shfl(az, s0l, 64), v0w = __shfl(aw, s0l, 64);
    float v1x = __shfl(ax, s1l, 64), v1y = __shfl(ay, s1l, 64);
    float v1z = __shfl(az, s1l, 64), v1w = __shfl(aw, s1l, 64);
    short8 af;
    if (r < 8) {
        af[0] = (short)f2bf(v0x); af[1] = (short)f2bf(v0y);
        af[2] = (short)f2bf(v0z); af[3] = (short)f2bf(v0w);
        af[4] = (short)f2bf(v1x); af[5] = (short)f2bf(v1y);
        af[6] = (short)f2bf(v1z); af[7] = (short)f2bf(v1w);
    } else {
        af = short8{0, 0, 0, 0, 0, 0, 0, 0};
    }
    float bias0 = blin[l & 15];
    float bias1 = blin[16 + (l & 15)];
    f32x4 c0, c1;
    #pragma unroll
    for (int q = 0; q < 4; q++) {
        int row = kb * 4 + q;
        float wvx = __shfl(wsum, (row << 3) & 63, 64);
        wvx = (row < 8) ? wvx : 0.f;
        c0[q] = bias0 * wvx;
        c1[q] = bias1 * wvx;
    }
    c0 = __builtin_amdgcn_mfma_f32_16x16x32_bf16(af, bf0, c0, 0, 0, 0);
    c1 = __builtin_amdgcn_mfma_f32_16x16x32_bf16(af, bf1, c1, 0, 0, 0);
    if (l < 32) {
        size_t rowbase = (((size_t)bi << 16) | g0) + (t >> 6) * 8;
        #pragma unroll
        for (int q = 0; q < 4; q++) {
            size_t rr = rowbase + (l >> 4) * 4 + q;
            __builtin_nontemporal_store(c0[q], &out[rr * NC + (l & 15)]);
            __builtin_nontemporal_store(c1[q], &out[rr * NC + 16 + (l & 15)]);
        }
    }
}

extern "C" void kernel_launch(void* const* d_in, const int* in_sizes, int n_in,
                              void* d_out, int out_size, void* d_ws, size_t ws_size,
                              hipStream_t stream)
{
    const float* features = (const float*)d_in[0];
    const float* xy       = (const float*)d_in[1];
    const float* ext      = (const float*)d_in[2];
    const float* Wlin     = (const float*)d_in[3];
    const float* blin     = (const float*)d_in[4];
    float* out = (float*)d_out;

    char* ws = (char*)d_ws;
    float*          At     = (float*)(ws + OFF_AT);
    unsigned int*   ptot   = (unsigned int*)(ws + OFF_PTOT);
    unsigned int*   pbase  = (unsigned int*)(ws + OFF_PBASE);
    unsigned int*   gsc    = (unsigned int*)(ws + OFF_GSC);
    unsigned int*   start  = (unsigned int*)(ws + OFF_START);
    unsigned int*   lstart = (unsigned int*)(ws + OFF_LSTART);
    unsigned short* pixarr = (unsigned short*)(ws + OFF_PIX);
    unsigned int*   sorted = (unsigned int*)(ws + OFF_SORT);
    unsigned int*   parts  = (unsigned int*)(ws + OFF_PARTS);
    unsigned short* fb16   = (unsigned short*)(ws + OFF_FB16);

    static const size_t k4a_lds = (96 + 32 * CAP4A) * sizeof(unsigned int);
    static const size_t k4c_lds = (K4BINS + K4CAP) * sizeof(unsigned int);
    hipFuncSetAttribute((const void*)k4a_part,
                        hipFuncAttributeMaxDynamicSharedMemorySize, (int)k4a_lds);
    hipFuncSetAttribute((const void*)k4c_fill,
                        hipFuncAttributeMaxDynamicSharedMemorySize, (int)k4c_lds);

    k1_pix<<<16385, 256, 0, stream>>>((const float2*)xy, pixarr, ext,
                                      out + STACKED_ELEMS, At);

    hipMemsetAsync(gsc, 0, 1024 * sizeof(unsigned int), stream);
    k4a_part<<<NBI * 16, 1024, k4a_lds, stream>>>(pixarr, gsc, parts);
    k4h_hist<<<1024, 1024, 0, stream>>>(gsc, parts, lstart, ptot);
    k4s_scan<<<1, 64, 0, stream>>>(ptot, pbase, start);
    k4c_fill<<<1024, 1024, k4c_lds, stream>>>(gsc, parts, lstart, pbase, ptot,
                                              sorted, start);

    for (int b0 = 0; b0 < NB; b0 += 2) {
        const float* src = features + (((size_t)b0) << 19) * NC;
        kf_conv<<<8192, 256, 0, stream>>>(src, (ushort4*)fb16);     // 2 slabs
        b_gather<<<32768, 256, 0, stream>>>(fb16, pixarr, start, sorted,
                                            Wlin, blin, At, out, b0);
    }
}